// Round 14
// baseline (2120.329 us; speedup 1.0000x reference)
//
#include <hip/hip_runtime.h>

#define NFFT  16384
#define NH2   8192      // half-size complex FFT
#define LSIG  8192
#define NH    1024
#define NTH   512

__device__ __forceinline__ int SWC(int ci) { return ci ^ (((ci >> 4) & 7) << 1); }
__device__ __forceinline__ int PADI(int i) { return i + (i >> 5); }   // fallback layout

struct cplx { float x, y; };
__device__ __forceinline__ cplx cadd(cplx a, cplx b){ return {a.x+b.x, a.y+b.y}; }
__device__ __forceinline__ cplx csub(cplx a, cplx b){ return {a.x-b.x, a.y-b.y}; }
__device__ __forceinline__ cplx cmul(cplx a, cplx b){ return {a.x*b.x - a.y*b.y, a.x*b.y + a.y*b.x}; }

template<int V> struct ic { static constexpr int value = V; };
template<int Start, int End, typename F>
__device__ __forceinline__ void cfor(F&& f) {
  if constexpr (Start < End) { f(ic<Start>{}); cfor<Start+1, End>(static_cast<F&&>(f)); }
}

constexpr float W32C32[32] = {
  1.0f, 0.9807852804f, 0.9238795325f, 0.8314696123f,
  0.7071067812f, 0.5555702330f, 0.3826834324f, 0.1950903220f,
  0.0f, -0.1950903220f, -0.3826834324f, -0.5555702330f,
  -0.7071067812f, -0.8314696123f, -0.9238795325f, -0.9807852804f,
  -1.0f, -0.9807852804f, -0.9238795325f, -0.8314696123f,
  -0.7071067812f, -0.5555702330f, -0.3826834324f, -0.1950903220f,
  0.0f, 0.1950903220f, 0.3826834324f, 0.5555702330f,
  0.7071067812f, 0.8314696123f, 0.9238795325f, 0.9807852804f };
constexpr float W32S32[32] = {
  0.0f, 0.1950903220f, 0.3826834324f, 0.5555702330f,
  0.7071067812f, 0.8314696123f, 0.9238795325f, 0.9807852804f,
  1.0f, 0.9807852804f, 0.9238795325f, 0.8314696123f,
  0.7071067812f, 0.5555702330f, 0.3826834324f, 0.1950903220f,
  0.0f, -0.1950903220f, -0.3826834324f, -0.5555702330f,
  -0.7071067812f, -0.8314696123f, -0.9238795325f, -0.9807852804f,
  -1.0f, -0.9807852804f, -0.9238795325f, -0.8314696123f,
  -0.7071067812f, -0.5555702330f, -0.3826834324f, -0.1950903220f };
constexpr int BR3[8] = {0,4,2,6,1,5,3,7};

template<int KK, bool INV>
__device__ __forceinline__ cplx twid(cplx d) {
  constexpr int K = KK & 31;
  if constexpr (K == 0)       return d;
  else if constexpr (K == 8)  { if constexpr (INV) return cplx{-d.y, d.x}; else return cplx{d.y, -d.x}; }
  else if constexpr (K == 16) return cplx{-d.x, -d.y};
  else if constexpr (K == 24) { if constexpr (INV) return cplx{d.y, -d.x}; else return cplx{-d.y, d.x}; }
  else {
    constexpr float c = W32C32[K];
    constexpr float s = INV ? W32S32[K] : -W32S32[K];
    return cmul(d, cplx{c, s});
  }
}

template<int N, int SP, bool INV>
__device__ __forceinline__ void fft_pass(cplx* z) {
  #pragma unroll
  for (int b = 0; b < N; b += 2*SP) {
    cfor<0, SP>([&](auto rc){
      constexpr int r = decltype(rc)::value;
      constexpr int KK = r * (16 / SP);
      if constexpr (!INV) {
        cplx u = z[b+r], v = z[b+r+SP];
        z[b+r]    = cadd(u, v);
        z[b+r+SP] = twid<KK,false>(csub(u, v));
      } else {
        cplx t0 = z[b+r], t1 = z[b+r+SP];
        cplx w = twid<KK,true>(t1);
        z[b+r]    = cadd(t0, w);
        z[b+r+SP] = csub(t0, w);
      }
    });
  }
}

template<int N, bool INV>
__device__ __forceinline__ void fft_regs(cplx* z) {
  if constexpr (!INV) {
    if constexpr (N >= 32) fft_pass<N,16,false>(z);
    if constexpr (N >= 16) fft_pass<N, 8,false>(z);
    if constexpr (N >=  8) fft_pass<N, 4,false>(z);
    if constexpr (N >=  4) fft_pass<N, 2,false>(z);
    fft_pass<N,1,false>(z);
  } else {
    fft_pass<N,1,true>(z);
    if constexpr (N >=  4) fft_pass<N, 2,true>(z);
    if constexpr (N >=  8) fft_pass<N, 4,true>(z);
    if constexpr (N >= 16) fft_pass<N, 8,true>(z);
    if constexpr (N >= 32) fft_pass<N,16,true>(z);
  }
}

// Paired radix-8 LDS stage for the 8192-pt FFT. S in {1024,128,16} complexes.
// 1024 butterflies = 512 pairs = one pair/thread. All b128, XOR-swizzled.
// Register shape ~88 live (A[8]+B[8]+wa+wb) — proven no-spill (round 10).
template<int S, bool INV>
__device__ __forceinline__ void stage8h(float2* sz, int tid) {
  const float ang1 = (INV ? 2.0f : -2.0f) * 3.14159265358979f / (float)(8 * S);
  int bf = 2 * tid;
  int q = bf / S;
  int r = bf - q * S;                 // even, r+1 < S
  int base = q * (8 * S) + r;
  float ta = ang1 * (float)r;
  float tb = ang1 * (float)(r + 1);
  cplx w1a = {__cosf(ta), __sinf(ta)};
  cplx w1b = {__cosf(tb), __sinf(tb)};
  cplx wa[8], wb[8];
  wa[1]=w1a; wa[2]=cmul(w1a,w1a); wa[3]=cmul(wa[2],w1a); wa[4]=cmul(wa[2],wa[2]);
  wa[5]=cmul(wa[4],wa[1]); wa[6]=cmul(wa[4],wa[2]); wa[7]=cmul(wa[4],wa[3]);
  wb[1]=w1b; wb[2]=cmul(w1b,w1b); wb[3]=cmul(wb[2],w1b); wb[4]=cmul(wb[2],wb[2]);
  wb[5]=cmul(wb[4],wb[1]); wb[6]=cmul(wb[4],wb[2]); wb[7]=cmul(wb[4],wb[3]);

  cplx A[8], B[8];
  if constexpr (!INV) {
    cfor<0,8>([&](auto jc){ constexpr int j = decltype(jc)::value;
      float4 v = *reinterpret_cast<const float4*>(&sz[SWC(base + j*S)]);
      A[j] = {v.x, v.y}; B[j] = {v.z, v.w}; });
    fft_regs<8,false>(A);
    fft_regs<8,false>(B);
    cfor<0,8>([&](auto pc){ constexpr int p = decltype(pc)::value;
      constexpr int m = BR3[p];
      cplx oa, ob;
      if constexpr (m == 0) { oa = A[p]; ob = B[p]; }
      else { oa = cmul(A[p], wa[m]); ob = cmul(B[p], wb[m]); }
      *reinterpret_cast<float4*>(&sz[SWC(base + m*S)]) = make_float4(oa.x, oa.y, ob.x, ob.y); });
  } else {
    cfor<0,8>([&](auto pc){ constexpr int p = decltype(pc)::value;
      constexpr int m = BR3[p];
      float4 v = *reinterpret_cast<const float4*>(&sz[SWC(base + m*S)]);
      if constexpr (m == 0) { A[p] = {v.x, v.y}; B[p] = {v.z, v.w}; }
      else { A[p] = cmul(cplx{v.x, v.y}, wa[m]); B[p] = cmul(cplx{v.z, v.w}, wb[m]); } });
    fft_regs<8,true>(A);
    fft_regs<8,true>(B);
    cfor<0,8>([&](auto jc){ constexpr int j = decltype(jc)::value;
      *reinterpret_cast<float4*>(&sz[SWC(base + j*S)]) = make_float4(A[j].x, A[j].y, B[j].x, B[j].y); });
  }
}

// Radix-8 stage, S = 2 (M = 16). Sub-problem q = tid, pair r = (0,1): loads
// are adjacent complexes; ALL twiddles constexpr. ~40 live regs.
template<bool INV>
__device__ __forceinline__ void stage8_s2(float2* sz, int tid) {
  int base = tid * 16;
  cplx A[8], B[8];
  if constexpr (!INV) {
    cfor<0,8>([&](auto jc){ constexpr int j = decltype(jc)::value;
      float4 v = *reinterpret_cast<const float4*>(&sz[SWC(base + 2*j)]);
      A[j] = {v.x, v.y}; B[j] = {v.z, v.w}; });
    fft_regs<8,false>(A);
    fft_regs<8,false>(B);
    cfor<0,8>([&](auto pc){ constexpr int p = decltype(pc)::value;
      constexpr int m = BR3[p];
      cplx oa = A[p];
      cplx ob = twid<2*m, false>(B[p]);
      *reinterpret_cast<float4*>(&sz[SWC(base + 2*m)]) = make_float4(oa.x, oa.y, ob.x, ob.y); });
  } else {
    cfor<0,8>([&](auto pc){ constexpr int p = decltype(pc)::value;
      constexpr int m = BR3[p];
      float4 v = *reinterpret_cast<const float4*>(&sz[SWC(base + 2*m)]);
      A[p] = {v.x, v.y};
      B[p] = twid<2*m, true>(cplx{v.z, v.w}); });
    fft_regs<8,true>(A);
    fft_regs<8,true>(B);
    cfor<0,8>([&](auto jc){ constexpr int j = decltype(jc)::value;
      *reinterpret_cast<float4*>(&sz[SWC(base + 2*j)]) = make_float4(A[j].x, A[j].y, B[j].x, B[j].y); });
  }
}

// ---------- kernel 1: per-h K-spectrum halves Ke, Ko into d_ws --------------
__global__ __launch_bounds__(NTH)
void kfft_kernel(const float* __restrict__ kin, float2* __restrict__ kh) {
  __shared__ __align__(16) float2 sz[NH2];   // 64 KiB
  const int tid = threadIdx.x;
  const int h = blockIdx.x;
  const float* krow = kin + (size_t)h * LSIG;
  const float scl = 1.0f / (float)NFFT;
  const float ct = -2.0f * 3.14159265358979f / (float)NFFT;

  #pragma unroll 1
  for (int half = 0; half < 2; ++half) {
    asm volatile("" : "+r"(half));      // opaque -> no unroll, no cross-half scheduling
    if (half) __syncthreads();
    #pragma unroll
    for (int c = 0; c < 8; ++c) {
      int ci = 2 * (c * NTH + tid);
      float2 kr = *reinterpret_cast<const float2*>(krow + ci);
      if (half == 0) {
        *reinterpret_cast<float4*>(&sz[SWC(ci)]) = make_float4(kr.x, 0.f, kr.y, 0.f);
      } else {
        float t0 = ct * (float)ci, t1 = ct * (float)(ci + 1);
        *reinterpret_cast<float4*>(&sz[SWC(ci)]) =
          make_float4(kr.x * __cosf(t0), kr.x * __sinf(t0),
                      kr.y * __cosf(t1), kr.y * __sinf(t1));
      }
    }
    __syncthreads();
    stage8h<1024,false>(sz, tid); __syncthreads();
    stage8h< 128,false>(sz, tid); __syncthreads();
    stage8h<  16,false>(sz, tid); __syncthreads();
    stage8_s2<false>(sz, tid);    __syncthreads();

    float2* dst = kh + (size_t)h * NFFT + half * NH2;
    #pragma unroll
    for (int s = 0; s < 8; ++s) {
      int m = tid + NTH * s;        // pair index
      int ci = 2 * m;
      float4 v = *reinterpret_cast<const float4*>(&sz[SWC(ci)]);
      cplx p0 = {v.x, v.y}, p1 = {v.z, v.w};
      cplx e = cadd(p0, p1), o = csub(p0, p1);   // tail DFT2
      *reinterpret_cast<float4*>(dst + ci) =
        make_float4(e.x * scl, e.y * scl, o.x * scl, o.y * scl);
    }
  }
}

// ---------- kernel 2: conv. 64 KiB LDS -> 2 blocks/CU. A staged via out. ----
// asm clobbers prevent the compiler from (a) unrolling the half loop and
// (b) forwarding half-0's A-stores to half-1's readback — which recreated a
// 32-float/thread live range across the whole half-1 FFT (rounds 11-13 spill).
__global__ __launch_bounds__(NTH)
void conv_kernel(const float* __restrict__ u, const float2* __restrict__ kh,
                 float* __restrict__ out) {
  __shared__ __align__(16) float2 sz[NH2];   // 64 KiB
  const int tid = threadIdx.x;
  const int bid = blockIdx.x;
  const int h  = bid >> 2;            // 4 same-h blocks adjacent -> K-hat reuse
  const int pr = bid & 3;
  const float ct  = -2.0f * 3.14159265358979f / (float)NFFT;  // W^n
  const float cti =  2.0f * 3.14159265358979f / (float)NFFT;  // conj(W^r)

  const float* u0 = u + ((size_t)(2*pr) * NH + h) * LSIG;
  const float* u1 = u0 + (size_t)NH * LSIG;
  float* o0 = out + ((size_t)(2*pr) * NH + h) * LSIG;
  float* o1 = o0 + (size_t)NH * LSIG;

  #pragma unroll 1
  for (int half = 0; half < 2; ++half) {
    asm volatile("" : "+r"(half));      // opaque trip var -> loop stays rolled
    asm volatile("" ::: "memory");      // kill store->load forwarding of A
    if (half) __syncthreads();
    // ---- stage-in (odd half applies W^n pointwise) ----
    #pragma unroll
    for (int c = 0; c < 8; ++c) {
      int ci = 2 * (c * NTH + tid);
      float2 a = *reinterpret_cast<const float2*>(u0 + ci);
      float2 b = *reinterpret_cast<const float2*>(u1 + ci);
      if (half == 0) {
        *reinterpret_cast<float4*>(&sz[SWC(ci)]) = make_float4(a.x, b.x, a.y, b.y);
      } else {
        float t0 = ct * (float)ci, t1 = ct * (float)(ci + 1);
        cplx w0 = {__cosf(t0), __sinf(t0)};
        cplx w1 = {__cosf(t1), __sinf(t1)};
        cplx z0 = cmul(cplx{a.x, b.x}, w0);
        cplx z1 = cmul(cplx{a.y, b.y}, w1);
        *reinterpret_cast<float4*>(&sz[SWC(ci)]) = make_float4(z0.x, z0.y, z1.x, z1.y);
      }
    }
    __syncthreads();
    stage8h<1024,false>(sz, tid); __syncthreads();
    stage8h< 128,false>(sz, tid); __syncthreads();
    stage8h<  16,false>(sz, tid); __syncthreads();
    stage8_s2<false>(sz, tid);    __syncthreads();

    {   // fused reg-2 tail: DFT2 -> multiply K pair -> inverse DFT2 (~12 regs)
      const float2* kp = kh + (size_t)h * NFFT + half * NH2;
      #pragma unroll
      for (int s = 0; s < 8; ++s) {
        int m = tid + NTH * s;
        int ci = 2 * m;
        float4 v = *reinterpret_cast<const float4*>(&sz[SWC(ci)]);
        cplx p0 = {v.x, v.y}, p1 = {v.z, v.w};
        cplx e = cadd(p0, p1), o = csub(p0, p1);
        float4 kv = *reinterpret_cast<const float4*>(kp + ci);
        cplx E = cmul(e, cplx{kv.x, kv.y});
        cplx O = cmul(o, cplx{kv.z, kv.w});
        *reinterpret_cast<float4*>(&sz[SWC(ci)]) =
          make_float4(E.x + O.x, E.y + O.y, E.x - O.x, E.y - O.y);
      }
    }
    __syncthreads();
    stage8_s2<true>(sz, tid);    __syncthreads();
    stage8h<  16,true>(sz, tid); __syncthreads();
    stage8h< 128,true>(sz, tid); __syncthreads();
    stage8h<1024,true>(sz, tid); __syncthreads();

    if (half == 0) {
      // stage A through the output buffer (per-thread slots)
      cfor<0,4>([&](auto cc){ constexpr int c = decltype(cc)::value;
        int ci = 4 * (c * NTH + tid);
        float4 v0 = *reinterpret_cast<const float4*>(&sz[SWC(ci)]);
        float4 v1 = *reinterpret_cast<const float4*>(&sz[SWC(ci + 2)]);
        *reinterpret_cast<float4*>(o0 + ci) = make_float4(v0.x, v0.z, v1.x, v1.z);
        *reinterpret_cast<float4*>(o1 + ci) = make_float4(v0.y, v0.w, v1.y, v1.w); });
    } else {
      // combine y[r] = A[r] + conj(W^r)*B[r]; overwrite with final
      cfor<0,4>([&](auto cc){ constexpr int c = decltype(cc)::value;
        int ci = 4 * (c * NTH + tid);
        float4 v0 = *reinterpret_cast<const float4*>(&sz[SWC(ci)]);
        float4 v1 = *reinterpret_cast<const float4*>(&sz[SWC(ci + 2)]);
        cplx bb[4] = { {v0.x,v0.y}, {v0.z,v0.w}, {v1.x,v1.y}, {v1.z,v1.w} };
        float4 are = *reinterpret_cast<const float4*>(o0 + ci);   // own writes
        float4 aim = *reinterpret_cast<const float4*>(o1 + ci);
        float arr[4] = {are.x, are.y, are.z, are.w};
        float aii[4] = {aim.x, aim.y, aim.z, aim.w};
        float re[4], im[4];
        cfor<0,4>([&](auto tc){ constexpr int t = decltype(tc)::value;
          float tr = cti * (float)(ci + t);
          cplx cw = {__cosf(tr), __sinf(tr)};
          cplx y = cadd(cplx{arr[t], aii[t]}, cmul(bb[t], cw));
          re[t] = y.x; im[t] = y.y; });
        *reinterpret_cast<float4*>(o0 + ci) = make_float4(re[0], re[1], re[2], re[3]);
        *reinterpret_cast<float4*>(o1 + ci) = make_float4(im[0], im[1], im[2], im[3]); });
    }
  }
}

// ================= fallback (round-9 monolithic, known-good) ================
template<int S, bool INV>
__device__ __forceinline__ void stage8f(float* sre, float* sim, int tid) {
  const float ang1 = (INV ? 2.0f : -2.0f) * 3.14159265358979f / (float)(8 * S);
  #pragma unroll
  for (int it = 0; it < (NFFT/8)/NTH; ++it) {
    int bf = tid + it * NTH;
    int q = bf / S;
    int r = bf - q * S;
    int base = q * (8 * S) + r;
    float t = ang1 * (float)r;
    cplx w1 = {__cosf(t), __sinf(t)};
    cplx wp[8];
    wp[0] = {1.0f, 0.0f};
    wp[1] = w1; wp[2] = cmul(w1, w1); wp[3] = cmul(wp[2], w1); wp[4] = cmul(wp[2], wp[2]);
    wp[5] = cmul(wp[4], wp[1]); wp[6] = cmul(wp[4], wp[2]); wp[7] = cmul(wp[4], wp[3]);
    cplx a[8];
    if constexpr (!INV) {
      cfor<0,8>([&](auto jc){ constexpr int j = decltype(jc)::value;
        int idx = PADI(base + j*S); a[j] = {sre[idx], sim[idx]}; });
      fft_regs<8,false>(a);
      cfor<0,8>([&](auto pc){ constexpr int p = decltype(pc)::value;
        constexpr int m = BR3[p];
        cplx o; if constexpr (m == 0) o = a[p]; else o = cmul(a[p], wp[m]);
        int idx = PADI(base + m*S); sre[idx] = o.x; sim[idx] = o.y; });
    } else {
      cfor<0,8>([&](auto pc){ constexpr int p = decltype(pc)::value;
        constexpr int m = BR3[p];
        int idx = PADI(base + m*S); cplx v = {sre[idx], sim[idx]};
        if constexpr (m == 0) a[p] = v; else a[p] = cmul(v, wp[m]); });
      fft_regs<8,true>(a);
      cfor<0,8>([&](auto jc){ constexpr int j = decltype(jc)::value;
        int idx = PADI(base + j*S); sre[idx] = a[j].x; sim[idx] = a[j].y; });
    }
  }
}

template<bool INV>
__device__ __forceinline__ void stage8_s4f(float* sre, float* sim, int tid) {
  cfor<0,4>([&](auto rc){
    constexpr int r = decltype(rc)::value;
    int base = tid * 32 + r;
    cplx a[8];
    if constexpr (!INV) {
      cfor<0,8>([&](auto jc){ constexpr int j = decltype(jc)::value;
        int idx = PADI(base + j*4); a[j] = {sre[idx], sim[idx]}; });
      fft_regs<8,false>(a);
      cfor<0,8>([&](auto pc){ constexpr int p = decltype(pc)::value;
        constexpr int m = BR3[p];
        cplx o = twid<r*m, false>(a[p]);
        int idx = PADI(base + m*4); sre[idx] = o.x; sim[idx] = o.y; });
    } else {
      cfor<0,8>([&](auto pc){ constexpr int p = decltype(pc)::value;
        constexpr int m = BR3[p];
        int idx = PADI(base + m*4); cplx v = {sre[idx], sim[idx]};
        a[p] = twid<r*m, true>(v); });
      fft_regs<8,true>(a);
      cfor<0,8>([&](auto jc){ constexpr int j = decltype(jc)::value;
        int idx = PADI(base + j*4); sre[idx] = a[j].x; sim[idx] = a[j].y; });
    }
  });
}

__global__ __launch_bounds__(NTH)
void fftconv_fallback(const float* __restrict__ u, const float* __restrict__ kin,
                      float* __restrict__ out) {
  __shared__ float sre[NFFT + (NFFT >> 5)];
  __shared__ float sim[NFFT + (NFFT >> 5)];
  const int tid = threadIdx.x;
  const int bid = blockIdx.x;
  const int h  = bid >> 2;
  const int pr = bid & 3;

  const float* krow = kin + (size_t)h * LSIG;
  #pragma unroll
  for (int c = 0; c < 4; ++c) {
    int i0 = (c * NTH + tid) * 4;
    float4 v = *reinterpret_cast<const float4*>(krow + i0);
    int p0 = PADI(i0);
    sre[p0+0]=v.x; sre[p0+1]=v.y; sre[p0+2]=v.z; sre[p0+3]=v.w;
    sim[p0+0]=0.f; sim[p0+1]=0.f; sim[p0+2]=0.f; sim[p0+3]=0.f;
    int p1 = PADI(i0 + LSIG);
    sre[p1+0]=0.f; sre[p1+1]=0.f; sre[p1+2]=0.f; sre[p1+3]=0.f;
    sim[p1+0]=0.f; sim[p1+1]=0.f; sim[p1+2]=0.f; sim[p1+3]=0.f;
  }
  __syncthreads();
  stage8f<2048,false>(sre, sim, tid); __syncthreads();
  stage8f< 256,false>(sre, sim, tid); __syncthreads();
  stage8f<  32,false>(sre, sim, tid); __syncthreads();
  stage8_s4f<false>(sre, sim, tid);   __syncthreads();

  cplx kq[4][4];
  cplx kq2[4][4];
  const float scl = 1.0f / (float)NFFT;
  #pragma unroll
  for (int s = 0; s < 8; ++s) {
    int m = tid + NTH * s;
    int p = PADI(4 * m);
    cplx z[4] = { {sre[p+0], sim[p+0]}, {sre[p+1], sim[p+1]},
                  {sre[p+2], sim[p+2]}, {sre[p+3], sim[p+3]} };
    fft_regs<4,false>(z);
    #pragma unroll
    for (int e = 0; e < 4; ++e) {
      cplx v = {z[e].x*scl, z[e].y*scl};
      if (s < 4) kq[s][e] = v; else kq2[s-4][e] = v;
    }
  }
  __syncthreads();

  const float* u0 = u + ((size_t)(2*pr) * NH + h) * LSIG;
  const float* u1 = u0 + (size_t)NH * LSIG;
  #pragma unroll
  for (int c = 0; c < 4; ++c) {
    int i0 = (c * NTH + tid) * 4;
    float4 a = *reinterpret_cast<const float4*>(u0 + i0);
    float4 b = *reinterpret_cast<const float4*>(u1 + i0);
    int p0 = PADI(i0);
    sre[p0+0]=a.x; sre[p0+1]=a.y; sre[p0+2]=a.z; sre[p0+3]=a.w;
    sim[p0+0]=b.x; sim[p0+1]=b.y; sim[p0+2]=b.z; sim[p0+3]=b.w;
    int p1 = PADI(i0 + LSIG);
    sre[p1+0]=0.f; sre[p1+1]=0.f; sre[p1+2]=0.f; sre[p1+3]=0.f;
    sim[p1+0]=0.f; sim[p1+1]=0.f; sim[p1+2]=0.f; sim[p1+3]=0.f;
  }
  __syncthreads();
  stage8f<2048,false>(sre, sim, tid); __syncthreads();
  stage8f< 256,false>(sre, sim, tid); __syncthreads();
  stage8f<  32,false>(sre, sim, tid); __syncthreads();
  stage8_s4f<false>(sre, sim, tid);   __syncthreads();

  #pragma unroll
  for (int s = 0; s < 8; ++s) {
    int m = tid + NTH * s;
    int p = PADI(4 * m);
    cplx z[4] = { {sre[p+0], sim[p+0]}, {sre[p+1], sim[p+1]},
                  {sre[p+2], sim[p+2]}, {sre[p+3], sim[p+3]} };
    fft_regs<4,false>(z);
    #pragma unroll
    for (int e = 0; e < 4; ++e) z[e] = cmul(z[e], (s<4) ? kq[s][e] : kq2[s-4][e]);
    fft_regs<4,true>(z);
    #pragma unroll
    for (int e = 0; e < 4; ++e) { sre[p+e] = z[e].x; sim[p+e] = z[e].y; }
  }
  __syncthreads();
  stage8_s4f<true>(sre, sim, tid);   __syncthreads();
  stage8f<  32,true>(sre, sim, tid); __syncthreads();
  stage8f< 256,true>(sre, sim, tid); __syncthreads();
  stage8f<2048,true>(sre, sim, tid); __syncthreads();

  float* o0 = out + ((size_t)(2*pr) * NH + h) * LSIG;
  float* o1 = o0 + (size_t)NH * LSIG;
  #pragma unroll
  for (int c = 0; c < 4; ++c) {
    int i0 = (c * NTH + tid) * 4;
    int p0 = PADI(i0);
    float4 a = {sre[p0], sre[p0+1], sre[p0+2], sre[p0+3]};
    float4 b = {sim[p0], sim[p0+1], sim[p0+2], sim[p0+3]};
    *reinterpret_cast<float4*>(o0 + i0) = a;
    *reinterpret_cast<float4*>(o1 + i0) = b;
  }
}

extern "C" void kernel_launch(void* const* d_in, const int* in_sizes, int n_in,
                              void* d_out, int out_size, void* d_ws, size_t ws_size,
                              hipStream_t stream) {
  (void)in_sizes; (void)n_in; (void)out_size;
  const float* u = (const float*)d_in[0];
  const float* k = (const float*)d_in[1];
  float* out = (float*)d_out;
  const size_t need = (size_t)NH * NFFT * sizeof(float2);   // 128 MiB
  if (ws_size >= need) {
    hipLaunchKernelGGL(kfft_kernel, dim3(NH),   dim3(NTH), 0, stream, k, (float2*)d_ws);
    hipLaunchKernelGGL(conv_kernel, dim3(4096), dim3(NTH), 0, stream, u, (const float2*)d_ws, out);
  } else {
    hipLaunchKernelGGL(fftconv_fallback, dim3(4096), dim3(NTH), 0, stream, u, k, out);
  }
}

// Round 15
// 431.021 us; speedup vs baseline: 4.9193x; 4.9193x over previous
//
#include <hip/hip_runtime.h>

#define NFFT 16384
#define LSIG 8192
#define NH   1024
#define NTH  512
#define LDSC (NFFT + ((NFFT >> 5) << 1))   // 17408 complexes, pad 2/32, b128-safe

__device__ __forceinline__ int PADC(int i) { return i + ((i >> 5) << 1); }
__device__ __forceinline__ int PADI(int i) { return i + (i >> 5); }   // fallback

struct cplx { float x, y; };
__device__ __forceinline__ cplx cadd(cplx a, cplx b){ return {a.x+b.x, a.y+b.y}; }
__device__ __forceinline__ cplx csub(cplx a, cplx b){ return {a.x-b.x, a.y-b.y}; }
__device__ __forceinline__ cplx cmul(cplx a, cplx b){ return {a.x*b.x - a.y*b.y, a.x*b.y + a.y*b.x}; }

template<int V> struct ic { static constexpr int value = V; };
template<int Start, int End, typename F>
__device__ __forceinline__ void cfor(F&& f) {
  if constexpr (Start < End) { f(ic<Start>{}); cfor<Start+1, End>(static_cast<F&&>(f)); }
}

constexpr float W32C32[32] = {
  1.0f, 0.9807852804f, 0.9238795325f, 0.8314696123f,
  0.7071067812f, 0.5555702330f, 0.3826834324f, 0.1950903220f,
  0.0f, -0.1950903220f, -0.3826834324f, -0.5555702330f,
  -0.7071067812f, -0.8314696123f, -0.9238795325f, -0.9807852804f,
  -1.0f, -0.9807852804f, -0.9238795325f, -0.8314696123f,
  -0.7071067812f, -0.5555702330f, -0.3826834324f, -0.1950903220f,
  0.0f, 0.1950903220f, 0.3826834324f, 0.5555702330f,
  0.7071067812f, 0.8314696123f, 0.9238795325f, 0.9807852804f };
constexpr float W32S32[32] = {
  0.0f, 0.1950903220f, 0.3826834324f, 0.5555702330f,
  0.7071067812f, 0.8314696123f, 0.9238795325f, 0.9807852804f,
  1.0f, 0.9807852804f, 0.9238795325f, 0.8314696123f,
  0.7071067812f, 0.5555702330f, 0.3826834324f, 0.1950903220f,
  0.0f, -0.1950903220f, -0.3826834324f, -0.5555702330f,
  -0.7071067812f, -0.8314696123f, -0.9238795325f, -0.9807852804f,
  -1.0f, -0.9807852804f, -0.9238795325f, -0.8314696123f,
  -0.7071067812f, -0.5555702330f, -0.3826834324f, -0.1950903220f };
constexpr int BR3[8] = {0,4,2,6,1,5,3,7};

template<int KK, bool INV>
__device__ __forceinline__ cplx twid(cplx d) {
  constexpr int K = KK & 31;
  if constexpr (K == 0)       return d;
  else if constexpr (K == 8)  { if constexpr (INV) return cplx{-d.y, d.x}; else return cplx{d.y, -d.x}; }
  else if constexpr (K == 16) return cplx{-d.x, -d.y};
  else if constexpr (K == 24) { if constexpr (INV) return cplx{d.y, -d.x}; else return cplx{-d.y, d.x}; }
  else {
    constexpr float c = W32C32[K];
    constexpr float s = INV ? W32S32[K] : -W32S32[K];
    return cmul(d, cplx{c, s});
  }
}

template<int N, int SP, bool INV>
__device__ __forceinline__ void fft_pass(cplx* z) {
  #pragma unroll
  for (int b = 0; b < N; b += 2*SP) {
    cfor<0, SP>([&](auto rc){
      constexpr int r = decltype(rc)::value;
      constexpr int KK = r * (16 / SP);
      if constexpr (!INV) {
        cplx u = z[b+r], v = z[b+r+SP];
        z[b+r]    = cadd(u, v);
        z[b+r+SP] = twid<KK,false>(csub(u, v));
      } else {
        cplx t0 = z[b+r], t1 = z[b+r+SP];
        cplx w = twid<KK,true>(t1);
        z[b+r]    = cadd(t0, w);
        z[b+r+SP] = csub(t0, w);
      }
    });
  }
}

template<int N, bool INV>
__device__ __forceinline__ void fft_regs(cplx* z) {
  if constexpr (!INV) {
    if constexpr (N >= 32) fft_pass<N,16,false>(z);
    if constexpr (N >= 16) fft_pass<N, 8,false>(z);
    if constexpr (N >=  8) fft_pass<N, 4,false>(z);
    if constexpr (N >=  4) fft_pass<N, 2,false>(z);
    fft_pass<N,1,false>(z);
  } else {
    fft_pass<N,1,true>(z);
    if constexpr (N >=  4) fft_pass<N, 2,true>(z);
    if constexpr (N >=  8) fft_pass<N, 4,true>(z);
    if constexpr (N >= 16) fft_pass<N, 8,true>(z);
    if constexpr (N >= 32) fft_pass<N,16,true>(z);
  }
}

// Paired radix-8 LDS stage (round-10 register shape, proven no-spill).
template<int S, bool INV>
__device__ __forceinline__ void stage8p(float2* sz, int tid) {
  const float ang1 = (INV ? 2.0f : -2.0f) * 3.14159265358979f / (float)(8 * S);
  #pragma unroll 1
  for (int it = 0; it < 2; ++it) {
    int pp = tid + it * NTH;
    int bf = 2 * pp;
    int q = bf / S;
    int r = bf - q * S;
    int base = q * (8 * S) + r;
    float ta = ang1 * (float)r;
    float tb = ang1 * (float)(r + 1);
    cplx w1a = {__cosf(ta), __sinf(ta)};
    cplx w1b = {__cosf(tb), __sinf(tb)};
    cplx wa[8], wb[8];
    wa[1]=w1a; wa[2]=cmul(w1a,w1a); wa[3]=cmul(wa[2],w1a); wa[4]=cmul(wa[2],wa[2]);
    wa[5]=cmul(wa[4],wa[1]); wa[6]=cmul(wa[4],wa[2]); wa[7]=cmul(wa[4],wa[3]);
    wb[1]=w1b; wb[2]=cmul(w1b,w1b); wb[3]=cmul(wb[2],w1b); wb[4]=cmul(wb[2],wb[2]);
    wb[5]=cmul(wb[4],wb[1]); wb[6]=cmul(wb[4],wb[2]); wb[7]=cmul(wb[4],wb[3]);

    cplx A[8], B[8];
    if constexpr (!INV) {
      cfor<0,8>([&](auto jc){ constexpr int j = decltype(jc)::value;
        float4 v = *reinterpret_cast<const float4*>(&sz[PADC(base + j*S)]);
        A[j] = {v.x, v.y}; B[j] = {v.z, v.w}; });
      fft_regs<8,false>(A);
      fft_regs<8,false>(B);
      cfor<0,8>([&](auto pc){ constexpr int p = decltype(pc)::value;
        constexpr int m = BR3[p];
        cplx oa, ob;
        if constexpr (m == 0) { oa = A[p]; ob = B[p]; }
        else { oa = cmul(A[p], wa[m]); ob = cmul(B[p], wb[m]); }
        *reinterpret_cast<float4*>(&sz[PADC(base + m*S)]) = make_float4(oa.x, oa.y, ob.x, ob.y); });
    } else {
      cfor<0,8>([&](auto pc){ constexpr int p = decltype(pc)::value;
        constexpr int m = BR3[p];
        float4 v = *reinterpret_cast<const float4*>(&sz[PADC(base + m*S)]);
        if constexpr (m == 0) { A[p] = {v.x, v.y}; B[p] = {v.z, v.w}; }
        else { A[p] = cmul(cplx{v.x, v.y}, wa[m]); B[p] = cmul(cplx{v.z, v.w}, wb[m]); } });
      fft_regs<8,true>(A);
      fft_regs<8,true>(B);
      cfor<0,8>([&](auto jc){ constexpr int j = decltype(jc)::value;
        *reinterpret_cast<float4*>(&sz[PADC(base + j*S)]) = make_float4(A[j].x, A[j].y, B[j].x, B[j].y); });
    }
  }
}

// Paired S=4 stage: thread-local (base = tid*32), constexpr twiddles.
template<bool INV>
__device__ __forceinline__ void stage8_s4p(float2* sz, int tid) {
  cfor<0,2>([&](auto rrc){
    constexpr int r0 = decltype(rrc)::value * 2;
    int base = tid * 32 + r0;
    cplx A[8], B[8];
    if constexpr (!INV) {
      cfor<0,8>([&](auto jc){ constexpr int j = decltype(jc)::value;
        float4 v = *reinterpret_cast<const float4*>(&sz[PADC(base + j*4)]);
        A[j] = {v.x, v.y}; B[j] = {v.z, v.w}; });
      fft_regs<8,false>(A);
      fft_regs<8,false>(B);
      cfor<0,8>([&](auto pc){ constexpr int p = decltype(pc)::value;
        constexpr int m = BR3[p];
        cplx oa = twid<r0*m, false>(A[p]);
        cplx ob = twid<(r0+1)*m, false>(B[p]);
        *reinterpret_cast<float4*>(&sz[PADC(base + m*4)]) = make_float4(oa.x, oa.y, ob.x, ob.y); });
    } else {
      cfor<0,8>([&](auto pc){ constexpr int p = decltype(pc)::value;
        constexpr int m = BR3[p];
        float4 v = *reinterpret_cast<const float4*>(&sz[PADC(base + m*4)]);
        A[p] = twid<r0*m, true>(cplx{v.x, v.y});
        B[p] = twid<(r0+1)*m, true>(cplx{v.z, v.w}); });
      fft_regs<8,true>(A);
      fft_regs<8,true>(B);
      cfor<0,8>([&](auto jc){ constexpr int j = decltype(jc)::value;
        *reinterpret_cast<float4*>(&sz[PADC(base + j*4)]) = make_float4(A[j].x, A[j].y, B[j].x, B[j].y); });
    }
  });
}

// ---------- kernel 1: K-spectrum (scrambled order, ci = 32*tid+4*s) ---------
__global__ __launch_bounds__(NTH)
void kfft_kernel(const float* __restrict__ kin, float2* __restrict__ kh) {
  __shared__ __align__(16) float2 sz[LDSC];
  const int tid = threadIdx.x;
  const int h = blockIdx.x;
  const float* krow = kin + (size_t)h * LSIG;
  const float ang1 = -2.0f * 3.14159265358979f / (float)NFFT;

  // stage 1 (S=2048) fused with global load; upper half of input is zero.
  #pragma unroll 1
  for (int it = 0; it < 2; ++it) {
    int base = 2*tid + 1024*it;
    cplx A[8], B[8];
    cfor<0,4>([&](auto jc){ constexpr int j = decltype(jc)::value;
      float2 kr = *reinterpret_cast<const float2*>(krow + base + j*2048);
      A[j] = {kr.x, 0.f}; B[j] = {kr.y, 0.f}; });
    cfor<0,4>([&](auto jc){ constexpr int j = decltype(jc)::value;   // half-zero SP=4
      A[j+4] = twid<4*j,false>(A[j]);
      B[j+4] = twid<4*j,false>(B[j]); });
    fft_pass<8,2,false>(A); fft_pass<8,1,false>(A);
    fft_pass<8,2,false>(B); fft_pass<8,1,false>(B);
    float ta = ang1 * (float)base, tb = ang1 * (float)(base + 1);
    cplx w1a = {__cosf(ta), __sinf(ta)};
    cplx w1b = {__cosf(tb), __sinf(tb)};
    cplx wa[8], wb[8];
    wa[1]=w1a; wa[2]=cmul(w1a,w1a); wa[3]=cmul(wa[2],w1a); wa[4]=cmul(wa[2],wa[2]);
    wa[5]=cmul(wa[4],wa[1]); wa[6]=cmul(wa[4],wa[2]); wa[7]=cmul(wa[4],wa[3]);
    wb[1]=w1b; wb[2]=cmul(w1b,w1b); wb[3]=cmul(wb[2],w1b); wb[4]=cmul(wb[2],wb[2]);
    wb[5]=cmul(wb[4],wb[1]); wb[6]=cmul(wb[4],wb[2]); wb[7]=cmul(wb[4],wb[3]);
    cfor<0,8>([&](auto pc){ constexpr int p = decltype(pc)::value;
      constexpr int m = BR3[p];
      cplx oa, ob;
      if constexpr (m == 0) { oa = A[p]; ob = B[p]; }
      else { oa = cmul(A[p], wa[m]); ob = cmul(B[p], wb[m]); }
      *reinterpret_cast<float4*>(&sz[PADC(base + m*2048)]) = make_float4(oa.x, oa.y, ob.x, ob.y); });
  }
  __syncthreads();
  stage8p< 256,false>(sz, tid); __syncthreads();
  stage8p<  32,false>(sz, tid); __syncthreads();
  stage8_s4p<false>(sz, tid);               // thread-local, no barrier needed

  const float scl = 1.0f / (float)NFFT;
  float2* row = kh + (size_t)h * NFFT;
  #pragma unroll
  for (int s = 0; s < 8; ++s) {             // quads in this thread's 32 complexes
    int ci = 32*tid + 4*s;
    float4 f0 = *reinterpret_cast<const float4*>(&sz[PADC(ci)]);
    float4 f1 = *reinterpret_cast<const float4*>(&sz[PADC(ci + 2)]);
    cplx z[4] = { {f0.x, f0.y}, {f0.z, f0.w}, {f1.x, f1.y}, {f1.z, f1.w} };
    fft_regs<4,false>(z);
    *reinterpret_cast<float4*>(row + ci)     = make_float4(z[0].x*scl, z[0].y*scl, z[1].x*scl, z[1].y*scl);
    *reinterpret_cast<float4*>(row + ci + 2) = make_float4(z[2].x*scl, z[2].y*scl, z[3].x*scl, z[3].y*scl);
  }
}

// ---------- kernel 2: conv (round-10 core + fused stage-1 I/O + merged tail)
__global__ __launch_bounds__(NTH)
void conv_kernel(const float* __restrict__ u, const float2* __restrict__ kh,
                 float* __restrict__ out) {
  __shared__ __align__(16) float2 sz[LDSC];
  const int tid = threadIdx.x;
  const int bid = blockIdx.x;
  const int h  = bid >> 2;            // 4 same-h blocks adjacent -> K-hat reuse
  const int pr = bid & 3;

  const float* u0 = u + ((size_t)(2*pr) * NH + h) * LSIG;
  const float* u1 = u0 + (size_t)NH * LSIG;
  float* o0 = out + ((size_t)(2*pr) * NH + h) * LSIG;
  float* o1 = o0 + (size_t)NH * LSIG;

  // ---- stage 1 forward, fused with global load (upper half zero) ----
  {
    const float ang1 = -2.0f * 3.14159265358979f / (float)NFFT;
    #pragma unroll 1
    for (int it = 0; it < 2; ++it) {
      int base = 2*tid + 1024*it;
      cplx A[8], B[8];
      cfor<0,4>([&](auto jc){ constexpr int j = decltype(jc)::value;
        float2 a2 = *reinterpret_cast<const float2*>(u0 + base + j*2048);
        float2 b2 = *reinterpret_cast<const float2*>(u1 + base + j*2048);
        A[j] = {a2.x, b2.x}; B[j] = {a2.y, b2.y}; });
      cfor<0,4>([&](auto jc){ constexpr int j = decltype(jc)::value;   // half-zero SP=4
        A[j+4] = twid<4*j,false>(A[j]);
        B[j+4] = twid<4*j,false>(B[j]); });
      fft_pass<8,2,false>(A); fft_pass<8,1,false>(A);
      fft_pass<8,2,false>(B); fft_pass<8,1,false>(B);
      float ta = ang1 * (float)base, tb = ang1 * (float)(base + 1);
      cplx w1a = {__cosf(ta), __sinf(ta)};
      cplx w1b = {__cosf(tb), __sinf(tb)};
      cplx wa[8], wb[8];
      wa[1]=w1a; wa[2]=cmul(w1a,w1a); wa[3]=cmul(wa[2],w1a); wa[4]=cmul(wa[2],wa[2]);
      wa[5]=cmul(wa[4],wa[1]); wa[6]=cmul(wa[4],wa[2]); wa[7]=cmul(wa[4],wa[3]);
      wb[1]=w1b; wb[2]=cmul(w1b,w1b); wb[3]=cmul(wb[2],w1b); wb[4]=cmul(wb[2],wb[2]);
      wb[5]=cmul(wb[4],wb[1]); wb[6]=cmul(wb[4],wb[2]); wb[7]=cmul(wb[4],wb[3]);
      cfor<0,8>([&](auto pc){ constexpr int p = decltype(pc)::value;
        constexpr int m = BR3[p];
        cplx oa, ob;
        if constexpr (m == 0) { oa = A[p]; ob = B[p]; }
        else { oa = cmul(A[p], wa[m]); ob = cmul(B[p], wb[m]); }
        *reinterpret_cast<float4*>(&sz[PADC(base + m*2048)]) = make_float4(oa.x, oa.y, ob.x, ob.y); });
    }
  }
  __syncthreads();
  stage8p< 256,false>(sz, tid); __syncthreads();
  stage8p<  32,false>(sz, tid); __syncthreads();

  // ---- merged thread-local tail: s4p -> DFT4*Khat*iDFT4 -> s4p-inv ----
  stage8_s4p<false>(sz, tid);
  {
    const float2* krow = kh + (size_t)h * NFFT;
    #pragma unroll
    for (int s = 0; s < 8; ++s) {
      int ci = 32*tid + 4*s;
      float4 f0 = *reinterpret_cast<const float4*>(&sz[PADC(ci)]);
      float4 f1 = *reinterpret_cast<const float4*>(&sz[PADC(ci + 2)]);
      cplx z[4] = { {f0.x, f0.y}, {f0.z, f0.w}, {f1.x, f1.y}, {f1.z, f1.w} };
      fft_regs<4,false>(z);
      float4 k0 = *reinterpret_cast<const float4*>(krow + ci);
      float4 k1 = *reinterpret_cast<const float4*>(krow + ci + 2);
      z[0] = cmul(z[0], cplx{k0.x, k0.y});
      z[1] = cmul(z[1], cplx{k0.z, k0.w});
      z[2] = cmul(z[2], cplx{k1.x, k1.y});
      z[3] = cmul(z[3], cplx{k1.z, k1.w});
      fft_regs<4,true>(z);
      *reinterpret_cast<float4*>(&sz[PADC(ci)])     = make_float4(z[0].x, z[0].y, z[1].x, z[1].y);
      *reinterpret_cast<float4*>(&sz[PADC(ci + 2)]) = make_float4(z[2].x, z[2].y, z[3].x, z[3].y);
    }
  }
  stage8_s4p<true>(sz, tid);
  __syncthreads();
  stage8p<  32,true>(sz, tid); __syncthreads();
  stage8p< 256,true>(sz, tid); __syncthreads();

  // ---- stage 1 inverse, fused with output (only first 8192 samples kept) ----
  {
    const float ang1 = 2.0f * 3.14159265358979f / (float)NFFT;
    #pragma unroll 1
    for (int it = 0; it < 2; ++it) {
      int base = 2*tid + 1024*it;
      float ta = ang1 * (float)base, tb = ang1 * (float)(base + 1);
      cplx w1a = {__cosf(ta), __sinf(ta)};
      cplx w1b = {__cosf(tb), __sinf(tb)};
      cplx wa[8], wb[8];
      wa[1]=w1a; wa[2]=cmul(w1a,w1a); wa[3]=cmul(wa[2],w1a); wa[4]=cmul(wa[2],wa[2]);
      wa[5]=cmul(wa[4],wa[1]); wa[6]=cmul(wa[4],wa[2]); wa[7]=cmul(wa[4],wa[3]);
      wb[1]=w1b; wb[2]=cmul(w1b,w1b); wb[3]=cmul(wb[2],w1b); wb[4]=cmul(wb[2],wb[2]);
      wb[5]=cmul(wb[4],wb[1]); wb[6]=cmul(wb[4],wb[2]); wb[7]=cmul(wb[4],wb[3]);
      cplx A[8], B[8];
      cfor<0,8>([&](auto pc){ constexpr int p = decltype(pc)::value;
        constexpr int m = BR3[p];
        float4 v = *reinterpret_cast<const float4*>(&sz[PADC(base + m*2048)]);
        if constexpr (m == 0) { A[p] = {v.x, v.y}; B[p] = {v.z, v.w}; }
        else { A[p] = cmul(cplx{v.x, v.y}, wa[m]); B[p] = cmul(cplx{v.z, v.w}, wb[m]); } });
      fft_pass<8,1,true>(A); fft_pass<8,2,true>(A);
      fft_pass<8,1,true>(B); fft_pass<8,2,true>(B);
      // final SP=4 pass, '+' half only (outputs j=0..3 are samples < 8192)
      cfor<0,4>([&](auto rc){ constexpr int r = decltype(rc)::value;
        cplx yA = cadd(A[r], twid<4*r,true>(A[r+4]));
        cplx yB = cadd(B[r], twid<4*r,true>(B[r+4]));
        *reinterpret_cast<float2*>(o0 + base + r*2048) = make_float2(yA.x, yB.x);
        *reinterpret_cast<float2*>(o1 + base + r*2048) = make_float2(yA.y, yB.y); });
    }
  }
}

// ================= fallback (round-9/10 monolithic, known-good) =============
template<int S, bool INV>
__device__ __forceinline__ void stage8f(float* sre, float* sim, int tid) {
  const float ang1 = (INV ? 2.0f : -2.0f) * 3.14159265358979f / (float)(8 * S);
  #pragma unroll
  for (int it = 0; it < (NFFT/8)/NTH; ++it) {
    int bf = tid + it * NTH;
    int q = bf / S;
    int r = bf - q * S;
    int base = q * (8 * S) + r;
    float t = ang1 * (float)r;
    cplx w1 = {__cosf(t), __sinf(t)};
    cplx wp[8];
    wp[0] = {1.0f, 0.0f};
    wp[1] = w1; wp[2] = cmul(w1, w1); wp[3] = cmul(wp[2], w1); wp[4] = cmul(wp[2], wp[2]);
    wp[5] = cmul(wp[4], wp[1]); wp[6] = cmul(wp[4], wp[2]); wp[7] = cmul(wp[4], wp[3]);
    cplx a[8];
    if constexpr (!INV) {
      cfor<0,8>([&](auto jc){ constexpr int j = decltype(jc)::value;
        int idx = PADI(base + j*S); a[j] = {sre[idx], sim[idx]}; });
      fft_regs<8,false>(a);
      cfor<0,8>([&](auto pc){ constexpr int p = decltype(pc)::value;
        constexpr int m = BR3[p];
        cplx o; if constexpr (m == 0) o = a[p]; else o = cmul(a[p], wp[m]);
        int idx = PADI(base + m*S); sre[idx] = o.x; sim[idx] = o.y; });
    } else {
      cfor<0,8>([&](auto pc){ constexpr int p = decltype(pc)::value;
        constexpr int m = BR3[p];
        int idx = PADI(base + m*S); cplx v = {sre[idx], sim[idx]};
        if constexpr (m == 0) a[p] = v; else a[p] = cmul(v, wp[m]); });
      fft_regs<8,true>(a);
      cfor<0,8>([&](auto jc){ constexpr int j = decltype(jc)::value;
        int idx = PADI(base + j*S); sre[idx] = a[j].x; sim[idx] = a[j].y; });
    }
  }
}

template<bool INV>
__device__ __forceinline__ void stage8_s4f(float* sre, float* sim, int tid) {
  cfor<0,4>([&](auto rc){
    constexpr int r = decltype(rc)::value;
    int base = tid * 32 + r;
    cplx a[8];
    if constexpr (!INV) {
      cfor<0,8>([&](auto jc){ constexpr int j = decltype(jc)::value;
        int idx = PADI(base + j*4); a[j] = {sre[idx], sim[idx]}; });
      fft_regs<8,false>(a);
      cfor<0,8>([&](auto pc){ constexpr int p = decltype(pc)::value;
        constexpr int m = BR3[p];
        cplx o = twid<r*m, false>(a[p]);
        int idx = PADI(base + m*4); sre[idx] = o.x; sim[idx] = o.y; });
    } else {
      cfor<0,8>([&](auto pc){ constexpr int p = decltype(pc)::value;
        constexpr int m = BR3[p];
        int idx = PADI(base + m*4); cplx v = {sre[idx], sim[idx]};
        a[p] = twid<r*m, true>(v); });
      fft_regs<8,true>(a);
      cfor<0,8>([&](auto jc){ constexpr int j = decltype(jc)::value;
        int idx = PADI(base + j*4); sre[idx] = a[j].x; sim[idx] = a[j].y; });
    }
  });
}

__global__ __launch_bounds__(NTH)
void fftconv_fallback(const float* __restrict__ u, const float* __restrict__ kin,
                      float* __restrict__ out) {
  __shared__ float sre[NFFT + (NFFT >> 5)];
  __shared__ float sim[NFFT + (NFFT >> 5)];
  const int tid = threadIdx.x;
  const int bid = blockIdx.x;
  const int h  = bid >> 2;
  const int pr = bid & 3;

  const float* krow = kin + (size_t)h * LSIG;
  #pragma unroll
  for (int c = 0; c < 4; ++c) {
    int i0 = (c * NTH + tid) * 4;
    float4 v = *reinterpret_cast<const float4*>(krow + i0);
    int p0 = PADI(i0);
    sre[p0+0]=v.x; sre[p0+1]=v.y; sre[p0+2]=v.z; sre[p0+3]=v.w;
    sim[p0+0]=0.f; sim[p0+1]=0.f; sim[p0+2]=0.f; sim[p0+3]=0.f;
    int p1 = PADI(i0 + LSIG);
    sre[p1+0]=0.f; sre[p1+1]=0.f; sre[p1+2]=0.f; sre[p1+3]=0.f;
    sim[p1+0]=0.f; sim[p1+1]=0.f; sim[p1+2]=0.f; sim[p1+3]=0.f;
  }
  __syncthreads();
  stage8f<2048,false>(sre, sim, tid); __syncthreads();
  stage8f< 256,false>(sre, sim, tid); __syncthreads();
  stage8f<  32,false>(sre, sim, tid); __syncthreads();
  stage8_s4f<false>(sre, sim, tid);   __syncthreads();

  cplx kq[4][4];
  cplx kq2[4][4];
  const float scl = 1.0f / (float)NFFT;
  #pragma unroll
  for (int s = 0; s < 8; ++s) {
    int m = tid + NTH * s;
    int p = PADI(4 * m);
    cplx z[4] = { {sre[p+0], sim[p+0]}, {sre[p+1], sim[p+1]},
                  {sre[p+2], sim[p+2]}, {sre[p+3], sim[p+3]} };
    fft_regs<4,false>(z);
    #pragma unroll
    for (int e = 0; e < 4; ++e) {
      cplx v = {z[e].x*scl, z[e].y*scl};
      if (s < 4) kq[s][e] = v; else kq2[s-4][e] = v;
    }
  }
  __syncthreads();

  const float* u0 = u + ((size_t)(2*pr) * NH + h) * LSIG;
  const float* u1 = u0 + (size_t)NH * LSIG;
  #pragma unroll
  for (int c = 0; c < 4; ++c) {
    int i0 = (c * NTH + tid) * 4;
    float4 a = *reinterpret_cast<const float4*>(u0 + i0);
    float4 b = *reinterpret_cast<const float4*>(u1 + i0);
    int p0 = PADI(i0);
    sre[p0+0]=a.x; sre[p0+1]=a.y; sre[p0+2]=a.z; sre[p0+3]=a.w;
    sim[p0+0]=b.x; sim[p0+1]=b.y; sim[p0+2]=b.z; sim[p0+3]=b.w;
    int p1 = PADI(i0 + LSIG);
    sre[p1+0]=0.f; sre[p1+1]=0.f; sre[p1+2]=0.f; sre[p1+3]=0.f;
    sim[p1+0]=0.f; sim[p1+1]=0.f; sim[p1+2]=0.f; sim[p1+3]=0.f;
  }
  __syncthreads();
  stage8f<2048,false>(sre, sim, tid); __syncthreads();
  stage8f< 256,false>(sre, sim, tid); __syncthreads();
  stage8f<  32,false>(sre, sim, tid); __syncthreads();
  stage8_s4f<false>(sre, sim, tid);   __syncthreads();

  #pragma unroll
  for (int s = 0; s < 8; ++s) {
    int m = tid + NTH * s;
    int p = PADI(4 * m);
    cplx z[4] = { {sre[p+0], sim[p+0]}, {sre[p+1], sim[p+1]},
                  {sre[p+2], sim[p+2]}, {sre[p+3], sim[p+3]} };
    fft_regs<4,false>(z);
    #pragma unroll
    for (int e = 0; e < 4; ++e) z[e] = cmul(z[e], (s<4) ? kq[s][e] : kq2[s-4][e]);
    fft_regs<4,true>(z);
    #pragma unroll
    for (int e = 0; e < 4; ++e) { sre[p+e] = z[e].x; sim[p+e] = z[e].y; }
  }
  __syncthreads();
  stage8_s4f<true>(sre, sim, tid);   __syncthreads();
  stage8f<  32,true>(sre, sim, tid); __syncthreads();
  stage8f< 256,true>(sre, sim, tid); __syncthreads();
  stage8f<2048,true>(sre, sim, tid); __syncthreads();

  float* o0 = out + ((size_t)(2*pr) * NH + h) * LSIG;
  float* o1 = o0 + (size_t)NH * LSIG;
  #pragma unroll
  for (int c = 0; c < 4; ++c) {
    int i0 = (c * NTH + tid) * 4;
    int p0 = PADI(i0);
    float4 a = {sre[p0], sre[p0+1], sre[p0+2], sre[p0+3]};
    float4 b = {sim[p0], sim[p0+1], sim[p0+2], sim[p0+3]};
    *reinterpret_cast<float4*>(o0 + i0) = a;
    *reinterpret_cast<float4*>(o1 + i0) = b;
  }
}

extern "C" void kernel_launch(void* const* d_in, const int* in_sizes, int n_in,
                              void* d_out, int out_size, void* d_ws, size_t ws_size,
                              hipStream_t stream) {
  (void)in_sizes; (void)n_in; (void)out_size;
  const float* u = (const float*)d_in[0];
  const float* k = (const float*)d_in[1];
  float* out = (float*)d_out;
  const size_t need = (size_t)NH * NFFT * sizeof(float2);   // 128 MiB
  if (ws_size >= need) {
    hipLaunchKernelGGL(kfft_kernel, dim3(NH),   dim3(NTH), 0, stream, k, (float2*)d_ws);
    hipLaunchKernelGGL(conv_kernel, dim3(4096), dim3(NTH), 0, stream, u, (const float2*)d_ws, out);
  } else {
    hipLaunchKernelGGL(fftconv_fallback, dim3(4096), dim3(NTH), 0, stream, u, k, out);
  }
}

// Round 16
// 374.816 us; speedup vs baseline: 5.6570x; 1.1500x over previous
//
#include <hip/hip_runtime.h>

#define NFFT 16384
#define LSIG 8192
#define NH   1024
#define NTH  512
#define LDSC (NFFT + ((NFFT >> 5) << 1))   // 17408 complexes, pad 2/32, b128-safe

__device__ __forceinline__ int PADC(int i) { return i + ((i >> 5) << 1); }
__device__ __forceinline__ int PADI(int i) { return i + (i >> 5); }   // fallback

struct cplx { float x, y; };
__device__ __forceinline__ cplx cadd(cplx a, cplx b){ return {a.x+b.x, a.y+b.y}; }
__device__ __forceinline__ cplx csub(cplx a, cplx b){ return {a.x-b.x, a.y-b.y}; }
__device__ __forceinline__ cplx cmul(cplx a, cplx b){ return {a.x*b.x - a.y*b.y, a.x*b.y + a.y*b.x}; }

template<int V> struct ic { static constexpr int value = V; };
template<int Start, int End, typename F>
__device__ __forceinline__ void cfor(F&& f) {
  if constexpr (Start < End) { f(ic<Start>{}); cfor<Start+1, End>(static_cast<F&&>(f)); }
}

constexpr float W32C32[32] = {
  1.0f, 0.9807852804f, 0.9238795325f, 0.8314696123f,
  0.7071067812f, 0.5555702330f, 0.3826834324f, 0.1950903220f,
  0.0f, -0.1950903220f, -0.3826834324f, -0.5555702330f,
  -0.7071067812f, -0.8314696123f, -0.9238795325f, -0.9807852804f,
  -1.0f, -0.9807852804f, -0.9238795325f, -0.8314696123f,
  -0.7071067812f, -0.5555702330f, -0.3826834324f, -0.1950903220f,
  0.0f, 0.1950903220f, 0.3826834324f, 0.5555702330f,
  0.7071067812f, 0.8314696123f, 0.9238795325f, 0.9807852804f };
constexpr float W32S32[32] = {
  0.0f, 0.1950903220f, 0.3826834324f, 0.5555702330f,
  0.7071067812f, 0.8314696123f, 0.9238795325f, 0.9807852804f,
  1.0f, 0.9807852804f, 0.9238795325f, 0.8314696123f,
  0.7071067812f, 0.5555702330f, 0.3826834324f, 0.1950903220f,
  0.0f, -0.1950903220f, -0.3826834324f, -0.5555702330f,
  -0.7071067812f, -0.8314696123f, -0.9238795325f, -0.9807852804f,
  -1.0f, -0.9807852804f, -0.9238795325f, -0.8314696123f,
  -0.7071067812f, -0.5555702330f, -0.3826834324f, -0.1950903220f };
constexpr int BR3[8] = {0,4,2,6,1,5,3,7};

template<int KK, bool INV>
__device__ __forceinline__ cplx twid(cplx d) {
  constexpr int K = KK & 31;
  if constexpr (K == 0)       return d;
  else if constexpr (K == 8)  { if constexpr (INV) return cplx{-d.y, d.x}; else return cplx{d.y, -d.x}; }
  else if constexpr (K == 16) return cplx{-d.x, -d.y};
  else if constexpr (K == 24) { if constexpr (INV) return cplx{d.y, -d.x}; else return cplx{-d.y, d.x}; }
  else {
    constexpr float c = W32C32[K];
    constexpr float s = INV ? W32S32[K] : -W32S32[K];
    return cmul(d, cplx{c, s});
  }
}

template<int N, int SP, bool INV>
__device__ __forceinline__ void fft_pass(cplx* z) {
  #pragma unroll
  for (int b = 0; b < N; b += 2*SP) {
    cfor<0, SP>([&](auto rc){
      constexpr int r = decltype(rc)::value;
      constexpr int KK = r * (16 / SP);
      if constexpr (!INV) {
        cplx u = z[b+r], v = z[b+r+SP];
        z[b+r]    = cadd(u, v);
        z[b+r+SP] = twid<KK,false>(csub(u, v));
      } else {
        cplx t0 = z[b+r], t1 = z[b+r+SP];
        cplx w = twid<KK,true>(t1);
        z[b+r]    = cadd(t0, w);
        z[b+r+SP] = csub(t0, w);
      }
    });
  }
}

template<int N, bool INV>
__device__ __forceinline__ void fft_regs(cplx* z) {
  if constexpr (!INV) {
    if constexpr (N >= 32) fft_pass<N,16,false>(z);
    if constexpr (N >= 16) fft_pass<N, 8,false>(z);
    if constexpr (N >=  8) fft_pass<N, 4,false>(z);
    if constexpr (N >=  4) fft_pass<N, 2,false>(z);
    fft_pass<N,1,false>(z);
  } else {
    fft_pass<N,1,true>(z);
    if constexpr (N >=  4) fft_pass<N, 2,true>(z);
    if constexpr (N >=  8) fft_pass<N, 4,true>(z);
    if constexpr (N >= 16) fft_pass<N, 8,true>(z);
    if constexpr (N >= 32) fft_pass<N,16,true>(z);
  }
}

// Paired radix-8 LDS stage (round-10 register shape, proven no-spill).
template<int S, bool INV>
__device__ __forceinline__ void stage8p(float2* sz, int tid) {
  const float ang1 = (INV ? 2.0f : -2.0f) * 3.14159265358979f / (float)(8 * S);
  #pragma unroll 1
  for (int it = 0; it < 2; ++it) {
    int pp = tid + it * NTH;
    int bf = 2 * pp;
    int q = bf / S;
    int r = bf - q * S;
    int base = q * (8 * S) + r;
    float ta = ang1 * (float)r;
    float tb = ang1 * (float)(r + 1);
    cplx w1a = {__cosf(ta), __sinf(ta)};
    cplx w1b = {__cosf(tb), __sinf(tb)};
    cplx wa[8], wb[8];
    wa[1]=w1a; wa[2]=cmul(w1a,w1a); wa[3]=cmul(wa[2],w1a); wa[4]=cmul(wa[2],wa[2]);
    wa[5]=cmul(wa[4],wa[1]); wa[6]=cmul(wa[4],wa[2]); wa[7]=cmul(wa[4],wa[3]);
    wb[1]=w1b; wb[2]=cmul(w1b,w1b); wb[3]=cmul(wb[2],w1b); wb[4]=cmul(wb[2],wb[2]);
    wb[5]=cmul(wb[4],wb[1]); wb[6]=cmul(wb[4],wb[2]); wb[7]=cmul(wb[4],wb[3]);

    cplx A[8], B[8];
    if constexpr (!INV) {
      cfor<0,8>([&](auto jc){ constexpr int j = decltype(jc)::value;
        float4 v = *reinterpret_cast<const float4*>(&sz[PADC(base + j*S)]);
        A[j] = {v.x, v.y}; B[j] = {v.z, v.w}; });
      fft_regs<8,false>(A);
      fft_regs<8,false>(B);
      cfor<0,8>([&](auto pc){ constexpr int p = decltype(pc)::value;
        constexpr int m = BR3[p];
        cplx oa, ob;
        if constexpr (m == 0) { oa = A[p]; ob = B[p]; }
        else { oa = cmul(A[p], wa[m]); ob = cmul(B[p], wb[m]); }
        *reinterpret_cast<float4*>(&sz[PADC(base + m*S)]) = make_float4(oa.x, oa.y, ob.x, ob.y); });
    } else {
      cfor<0,8>([&](auto pc){ constexpr int p = decltype(pc)::value;
        constexpr int m = BR3[p];
        float4 v = *reinterpret_cast<const float4*>(&sz[PADC(base + m*S)]);
        if constexpr (m == 0) { A[p] = {v.x, v.y}; B[p] = {v.z, v.w}; }
        else { A[p] = cmul(cplx{v.x, v.y}, wa[m]); B[p] = cmul(cplx{v.z, v.w}, wb[m]); } });
      fft_regs<8,true>(A);
      fft_regs<8,true>(B);
      cfor<0,8>([&](auto jc){ constexpr int j = decltype(jc)::value;
        *reinterpret_cast<float4*>(&sz[PADC(base + j*S)]) = make_float4(A[j].x, A[j].y, B[j].x, B[j].y); });
    }
  }
}

// S=32 stage with WAVE-LOCAL butterfly mapping: pp = 128*wave + lane + 64*it
// (bijective; identical per-lane r pattern to the old mapping -> same banks).
// Wave w then owns complexes [2048w, 2048w+2048), which contains its threads'
// s4p/quad ranges [32*tid, 32*tid+32) -> the whole s32..s32inv region is
// wave-synchronous (in-order LDS pipe) and needs NO block barrier.
template<bool INV>
__device__ __forceinline__ void stage8p32w(float2* sz, int tid) {
  const float ang1 = (INV ? 2.0f : -2.0f) * 3.14159265358979f / 256.0f;
  #pragma unroll 1
  for (int it = 0; it < 2; ++it) {
    int pp = 128 * (tid >> 6) + (tid & 63) + 64 * it;
    int bf = 2 * pp;
    int q = bf >> 5;
    int r = bf & 31;
    int base = q * 256 + r;
    float ta = ang1 * (float)r;
    float tb = ang1 * (float)(r + 1);
    cplx w1a = {__cosf(ta), __sinf(ta)};
    cplx w1b = {__cosf(tb), __sinf(tb)};
    cplx wa[8], wb[8];
    wa[1]=w1a; wa[2]=cmul(w1a,w1a); wa[3]=cmul(wa[2],w1a); wa[4]=cmul(wa[2],wa[2]);
    wa[5]=cmul(wa[4],wa[1]); wa[6]=cmul(wa[4],wa[2]); wa[7]=cmul(wa[4],wa[3]);
    wb[1]=w1b; wb[2]=cmul(w1b,w1b); wb[3]=cmul(wb[2],w1b); wb[4]=cmul(wb[2],wb[2]);
    wb[5]=cmul(wb[4],wb[1]); wb[6]=cmul(wb[4],wb[2]); wb[7]=cmul(wb[4],wb[3]);

    cplx A[8], B[8];
    if constexpr (!INV) {
      cfor<0,8>([&](auto jc){ constexpr int j = decltype(jc)::value;
        float4 v = *reinterpret_cast<const float4*>(&sz[PADC(base + j*32)]);
        A[j] = {v.x, v.y}; B[j] = {v.z, v.w}; });
      fft_regs<8,false>(A);
      fft_regs<8,false>(B);
      cfor<0,8>([&](auto pc){ constexpr int p = decltype(pc)::value;
        constexpr int m = BR3[p];
        cplx oa, ob;
        if constexpr (m == 0) { oa = A[p]; ob = B[p]; }
        else { oa = cmul(A[p], wa[m]); ob = cmul(B[p], wb[m]); }
        *reinterpret_cast<float4*>(&sz[PADC(base + m*32)]) = make_float4(oa.x, oa.y, ob.x, ob.y); });
    } else {
      cfor<0,8>([&](auto pc){ constexpr int p = decltype(pc)::value;
        constexpr int m = BR3[p];
        float4 v = *reinterpret_cast<const float4*>(&sz[PADC(base + m*32)]);
        if constexpr (m == 0) { A[p] = {v.x, v.y}; B[p] = {v.z, v.w}; }
        else { A[p] = cmul(cplx{v.x, v.y}, wa[m]); B[p] = cmul(cplx{v.z, v.w}, wb[m]); } });
      fft_regs<8,true>(A);
      fft_regs<8,true>(B);
      cfor<0,8>([&](auto jc){ constexpr int j = decltype(jc)::value;
        *reinterpret_cast<float4*>(&sz[PADC(base + j*32)]) = make_float4(A[j].x, A[j].y, B[j].x, B[j].y); });
    }
  }
}

// Paired S=4 stage: thread-local (base = tid*32), constexpr twiddles.
template<bool INV>
__device__ __forceinline__ void stage8_s4p(float2* sz, int tid) {
  cfor<0,2>([&](auto rrc){
    constexpr int r0 = decltype(rrc)::value * 2;
    int base = tid * 32 + r0;
    cplx A[8], B[8];
    if constexpr (!INV) {
      cfor<0,8>([&](auto jc){ constexpr int j = decltype(jc)::value;
        float4 v = *reinterpret_cast<const float4*>(&sz[PADC(base + j*4)]);
        A[j] = {v.x, v.y}; B[j] = {v.z, v.w}; });
      fft_regs<8,false>(A);
      fft_regs<8,false>(B);
      cfor<0,8>([&](auto pc){ constexpr int p = decltype(pc)::value;
        constexpr int m = BR3[p];
        cplx oa = twid<r0*m, false>(A[p]);
        cplx ob = twid<(r0+1)*m, false>(B[p]);
        *reinterpret_cast<float4*>(&sz[PADC(base + m*4)]) = make_float4(oa.x, oa.y, ob.x, ob.y); });
    } else {
      cfor<0,8>([&](auto pc){ constexpr int p = decltype(pc)::value;
        constexpr int m = BR3[p];
        float4 v = *reinterpret_cast<const float4*>(&sz[PADC(base + m*4)]);
        A[p] = twid<r0*m, true>(cplx{v.x, v.y});
        B[p] = twid<(r0+1)*m, true>(cplx{v.z, v.w});
      });
      fft_regs<8,true>(A);
      fft_regs<8,true>(B);
      cfor<0,8>([&](auto jc){ constexpr int j = decltype(jc)::value;
        *reinterpret_cast<float4*>(&sz[PADC(base + j*4)]) = make_float4(A[j].x, A[j].y, B[j].x, B[j].y); });
    }
  });
}

// ---------- kernel 1: K-spectrum, stored TRANSPOSED for coalesced conv reads:
// kh[h*NFFT + s*2048 + 4*tid + e]  (thread tid's quad s = spectrum 32tid+4s)
__global__ __launch_bounds__(NTH)
void kfft_kernel(const float* __restrict__ kin, float2* __restrict__ kh) {
  __shared__ __align__(16) float2 sz[LDSC];
  const int tid = threadIdx.x;
  const int h = blockIdx.x;
  const float* krow = kin + (size_t)h * LSIG;
  const float ang1 = -2.0f * 3.14159265358979f / (float)NFFT;

  // stage 1 (S=2048) fused with global load; upper half of input is zero.
  #pragma unroll 1
  for (int it = 0; it < 2; ++it) {
    int base = 2*tid + 1024*it;
    cplx A[8], B[8];
    cfor<0,4>([&](auto jc){ constexpr int j = decltype(jc)::value;
      float2 kr = *reinterpret_cast<const float2*>(krow + base + j*2048);
      A[j] = {kr.x, 0.f}; B[j] = {kr.y, 0.f}; });
    cfor<0,4>([&](auto jc){ constexpr int j = decltype(jc)::value;   // half-zero SP=4
      A[j+4] = twid<4*j,false>(A[j]);
      B[j+4] = twid<4*j,false>(B[j]); });
    fft_pass<8,2,false>(A); fft_pass<8,1,false>(A);
    fft_pass<8,2,false>(B); fft_pass<8,1,false>(B);
    float ta = ang1 * (float)base, tb = ang1 * (float)(base + 1);
    cplx w1a = {__cosf(ta), __sinf(ta)};
    cplx w1b = {__cosf(tb), __sinf(tb)};
    cplx wa[8], wb[8];
    wa[1]=w1a; wa[2]=cmul(w1a,w1a); wa[3]=cmul(wa[2],w1a); wa[4]=cmul(wa[2],wa[2]);
    wa[5]=cmul(wa[4],wa[1]); wa[6]=cmul(wa[4],wa[2]); wa[7]=cmul(wa[4],wa[3]);
    wb[1]=w1b; wb[2]=cmul(w1b,w1b); wb[3]=cmul(wb[2],w1b); wb[4]=cmul(wb[2],wb[2]);
    wb[5]=cmul(wb[4],wb[1]); wb[6]=cmul(wb[4],wb[2]); wb[7]=cmul(wb[4],wb[3]);
    cfor<0,8>([&](auto pc){ constexpr int p = decltype(pc)::value;
      constexpr int m = BR3[p];
      cplx oa, ob;
      if constexpr (m == 0) { oa = A[p]; ob = B[p]; }
      else { oa = cmul(A[p], wa[m]); ob = cmul(B[p], wb[m]); }
      *reinterpret_cast<float4*>(&sz[PADC(base + m*2048)]) = make_float4(oa.x, oa.y, ob.x, ob.y); });
  }
  __syncthreads();
  stage8p< 256,false>(sz, tid); __syncthreads();
  stage8p32w<false>(sz, tid);               // wave-local from here on
  stage8_s4p<false>(sz, tid);

  const float scl = 1.0f / (float)NFFT;
  float2* row = kh + (size_t)h * NFFT;
  #pragma unroll
  for (int s = 0; s < 8; ++s) {             // quads in this thread's 32 complexes
    int ci = 32*tid + 4*s;
    float4 f0 = *reinterpret_cast<const float4*>(&sz[PADC(ci)]);
    float4 f1 = *reinterpret_cast<const float4*>(&sz[PADC(ci + 2)]);
    cplx z[4] = { {f0.x, f0.y}, {f0.z, f0.w}, {f1.x, f1.y}, {f1.z, f1.w} };
    fft_regs<4,false>(z);
    float2* dst = row + s*2048 + 4*tid;     // transposed: coalesced write
    *reinterpret_cast<float4*>(dst)     = make_float4(z[0].x*scl, z[0].y*scl, z[1].x*scl, z[1].y*scl);
    *reinterpret_cast<float4*>(dst + 2) = make_float4(z[2].x*scl, z[2].y*scl, z[3].x*scl, z[3].y*scl);
  }
}

// ---------- kernel 2: conv (round-15 core; coalesced K-hat; 4 barriers) -----
__global__ __launch_bounds__(NTH)
void conv_kernel(const float* __restrict__ u, const float2* __restrict__ kh,
                 float* __restrict__ out) {
  __shared__ __align__(16) float2 sz[LDSC];
  const int tid = threadIdx.x;
  const int bid = blockIdx.x;
  const int h  = bid >> 2;            // 4 same-h blocks adjacent -> K-hat reuse
  const int pr = bid & 3;

  const float* u0 = u + ((size_t)(2*pr) * NH + h) * LSIG;
  const float* u1 = u0 + (size_t)NH * LSIG;
  float* o0 = out + ((size_t)(2*pr) * NH + h) * LSIG;
  float* o1 = o0 + (size_t)NH * LSIG;

  // ---- stage 1 forward, fused with global load (upper half zero) ----
  {
    const float ang1 = -2.0f * 3.14159265358979f / (float)NFFT;
    #pragma unroll 1
    for (int it = 0; it < 2; ++it) {
      int base = 2*tid + 1024*it;
      cplx A[8], B[8];
      cfor<0,4>([&](auto jc){ constexpr int j = decltype(jc)::value;
        float2 a2 = *reinterpret_cast<const float2*>(u0 + base + j*2048);
        float2 b2 = *reinterpret_cast<const float2*>(u1 + base + j*2048);
        A[j] = {a2.x, b2.x}; B[j] = {a2.y, b2.y}; });
      cfor<0,4>([&](auto jc){ constexpr int j = decltype(jc)::value;   // half-zero SP=4
        A[j+4] = twid<4*j,false>(A[j]);
        B[j+4] = twid<4*j,false>(B[j]); });
      fft_pass<8,2,false>(A); fft_pass<8,1,false>(A);
      fft_pass<8,2,false>(B); fft_pass<8,1,false>(B);
      float ta = ang1 * (float)base, tb = ang1 * (float)(base + 1);
      cplx w1a = {__cosf(ta), __sinf(ta)};
      cplx w1b = {__cosf(tb), __sinf(tb)};
      cplx wa[8], wb[8];
      wa[1]=w1a; wa[2]=cmul(w1a,w1a); wa[3]=cmul(wa[2],w1a); wa[4]=cmul(wa[2],wa[2]);
      wa[5]=cmul(wa[4],wa[1]); wa[6]=cmul(wa[4],wa[2]); wa[7]=cmul(wa[4],wa[3]);
      wb[1]=w1b; wb[2]=cmul(w1b,w1b); wb[3]=cmul(wb[2],w1b); wb[4]=cmul(wb[2],wb[2]);
      wb[5]=cmul(wb[4],wb[1]); wb[6]=cmul(wb[4],wb[2]); wb[7]=cmul(wb[4],wb[3]);
      cfor<0,8>([&](auto pc){ constexpr int p = decltype(pc)::value;
        constexpr int m = BR3[p];
        cplx oa, ob;
        if constexpr (m == 0) { oa = A[p]; ob = B[p]; }
        else { oa = cmul(A[p], wa[m]); ob = cmul(B[p], wb[m]); }
        *reinterpret_cast<float4*>(&sz[PADC(base + m*2048)]) = make_float4(oa.x, oa.y, ob.x, ob.y); });
    }
  }
  __syncthreads();
  stage8p< 256,false>(sz, tid); __syncthreads();

  // ---- wave-local region: s32 -> s4p -> quad*Khat -> s4p-inv -> s32-inv ----
  stage8p32w<false>(sz, tid);
  stage8_s4p<false>(sz, tid);
  {
    const float2* kp = kh + (size_t)h * NFFT;
    #pragma unroll
    for (int s = 0; s < 8; ++s) {
      int ci = 32*tid + 4*s;
      float4 f0 = *reinterpret_cast<const float4*>(&sz[PADC(ci)]);
      float4 f1 = *reinterpret_cast<const float4*>(&sz[PADC(ci + 2)]);
      cplx z[4] = { {f0.x, f0.y}, {f0.z, f0.w}, {f1.x, f1.y}, {f1.z, f1.w} };
      fft_regs<4,false>(z);
      const float2* kq = kp + s*2048 + 4*tid;          // coalesced (2KB/wave)
      float4 k0 = *reinterpret_cast<const float4*>(kq);
      float4 k1 = *reinterpret_cast<const float4*>(kq + 2);
      z[0] = cmul(z[0], cplx{k0.x, k0.y});
      z[1] = cmul(z[1], cplx{k0.z, k0.w});
      z[2] = cmul(z[2], cplx{k1.x, k1.y});
      z[3] = cmul(z[3], cplx{k1.z, k1.w});
      fft_regs<4,true>(z);
      *reinterpret_cast<float4*>(&sz[PADC(ci)])     = make_float4(z[0].x, z[0].y, z[1].x, z[1].y);
      *reinterpret_cast<float4*>(&sz[PADC(ci + 2)]) = make_float4(z[2].x, z[2].y, z[3].x, z[3].y);
    }
  }
  stage8_s4p<true>(sz, tid);
  stage8p32w<true>(sz, tid);
  __syncthreads();

  stage8p< 256,true>(sz, tid); __syncthreads();

  // ---- stage 1 inverse, fused with output (only first 8192 samples kept) ----
  {
    const float ang1 = 2.0f * 3.14159265358979f / (float)NFFT;
    #pragma unroll 1
    for (int it = 0; it < 2; ++it) {
      int base = 2*tid + 1024*it;
      float ta = ang1 * (float)base, tb = ang1 * (float)(base + 1);
      cplx w1a = {__cosf(ta), __sinf(ta)};
      cplx w1b = {__cosf(tb), __sinf(tb)};
      cplx wa[8], wb[8];
      wa[1]=w1a; wa[2]=cmul(w1a,w1a); wa[3]=cmul(wa[2],w1a); wa[4]=cmul(wa[2],wa[2]);
      wa[5]=cmul(wa[4],wa[1]); wa[6]=cmul(wa[4],wa[2]); wa[7]=cmul(wa[4],wa[3]);
      wb[1]=w1b; wb[2]=cmul(w1b,w1b); wb[3]=cmul(wb[2],w1b); wb[4]=cmul(wb[2],wb[2]);
      wb[5]=cmul(wb[4],wb[1]); wb[6]=cmul(wb[4],wb[2]); wb[7]=cmul(wb[4],wb[3]);
      cplx A[8], B[8];
      cfor<0,8>([&](auto pc){ constexpr int p = decltype(pc)::value;
        constexpr int m = BR3[p];
        float4 v = *reinterpret_cast<const float4*>(&sz[PADC(base + m*2048)]);
        if constexpr (m == 0) { A[p] = {v.x, v.y}; B[p] = {v.z, v.w}; }
        else { A[p] = cmul(cplx{v.x, v.y}, wa[m]); B[p] = cmul(cplx{v.z, v.w}, wb[m]); } });
      fft_pass<8,1,true>(A); fft_pass<8,2,true>(A);
      fft_pass<8,1,true>(B); fft_pass<8,2,true>(B);
      // final SP=4 pass, '+' half only (outputs j=0..3 are samples < 8192)
      cfor<0,4>([&](auto rc){ constexpr int r = decltype(rc)::value;
        cplx yA = cadd(A[r], twid<4*r,true>(A[r+4]));
        cplx yB = cadd(B[r], twid<4*r,true>(B[r+4]));
        *reinterpret_cast<float2*>(o0 + base + r*2048) = make_float2(yA.x, yB.x);
        *reinterpret_cast<float2*>(o1 + base + r*2048) = make_float2(yA.y, yB.y); });
    }
  }
}

// ================= fallback (round-9/10 monolithic, known-good) =============
template<int S, bool INV>
__device__ __forceinline__ void stage8f(float* sre, float* sim, int tid) {
  const float ang1 = (INV ? 2.0f : -2.0f) * 3.14159265358979f / (float)(8 * S);
  #pragma unroll
  for (int it = 0; it < (NFFT/8)/NTH; ++it) {
    int bf = tid + it * NTH;
    int q = bf / S;
    int r = bf - q * S;
    int base = q * (8 * S) + r;
    float t = ang1 * (float)r;
    cplx w1 = {__cosf(t), __sinf(t)};
    cplx wp[8];
    wp[0] = {1.0f, 0.0f};
    wp[1] = w1; wp[2] = cmul(w1, w1); wp[3] = cmul(wp[2], w1); wp[4] = cmul(wp[2], wp[2]);
    wp[5] = cmul(wp[4], wp[1]); wp[6] = cmul(wp[4], wp[2]); wp[7] = cmul(wp[4], wp[3]);
    cplx a[8];
    if constexpr (!INV) {
      cfor<0,8>([&](auto jc){ constexpr int j = decltype(jc)::value;
        int idx = PADI(base + j*S); a[j] = {sre[idx], sim[idx]}; });
      fft_regs<8,false>(a);
      cfor<0,8>([&](auto pc){ constexpr int p = decltype(pc)::value;
        constexpr int m = BR3[p];
        cplx o; if constexpr (m == 0) o = a[p]; else o = cmul(a[p], wp[m]);
        int idx = PADI(base + m*S); sre[idx] = o.x; sim[idx] = o.y; });
    } else {
      cfor<0,8>([&](auto pc){ constexpr int p = decltype(pc)::value;
        constexpr int m = BR3[p];
        int idx = PADI(base + m*S); cplx v = {sre[idx], sim[idx]};
        if constexpr (m == 0) a[p] = v; else a[p] = cmul(v, wp[m]); });
      fft_regs<8,true>(a);
      cfor<0,8>([&](auto jc){ constexpr int j = decltype(jc)::value;
        int idx = PADI(base + j*S); sre[idx] = a[j].x; sim[idx] = a[j].y; });
    }
  }
}

template<bool INV>
__device__ __forceinline__ void stage8_s4f(float* sre, float* sim, int tid) {
  cfor<0,4>([&](auto rc){
    constexpr int r = decltype(rc)::value;
    int base = tid * 32 + r;
    cplx a[8];
    if constexpr (!INV) {
      cfor<0,8>([&](auto jc){ constexpr int j = decltype(jc)::value;
        int idx = PADI(base + j*4); a[j] = {sre[idx], sim[idx]}; });
      fft_regs<8,false>(a);
      cfor<0,8>([&](auto pc){ constexpr int p = decltype(pc)::value;
        constexpr int m = BR3[p];
        cplx o = twid<r*m, false>(a[p]);
        int idx = PADI(base + m*4); sre[idx] = o.x; sim[idx] = o.y; });
    } else {
      cfor<0,8>([&](auto pc){ constexpr int p = decltype(pc)::value;
        constexpr int m = BR3[p];
        int idx = PADI(base + m*4); cplx v = {sre[idx], sim[idx]};
        a[p] = twid<r*m, true>(v); });
      fft_regs<8,true>(a);
      cfor<0,8>([&](auto jc){ constexpr int j = decltype(jc)::value;
        int idx = PADI(base + j*4); sre[idx] = a[j].x; sim[idx] = a[j].y; });
    }
  });
}

__global__ __launch_bounds__(NTH)
void fftconv_fallback(const float* __restrict__ u, const float* __restrict__ kin,
                      float* __restrict__ out) {
  __shared__ float sre[NFFT + (NFFT >> 5)];
  __shared__ float sim[NFFT + (NFFT >> 5)];
  const int tid = threadIdx.x;
  const int bid = blockIdx.x;
  const int h  = bid >> 2;
  const int pr = bid & 3;

  const float* krow = kin + (size_t)h * LSIG;
  #pragma unroll
  for (int c = 0; c < 4; ++c) {
    int i0 = (c * NTH + tid) * 4;
    float4 v = *reinterpret_cast<const float4*>(krow + i0);
    int p0 = PADI(i0);
    sre[p0+0]=v.x; sre[p0+1]=v.y; sre[p0+2]=v.z; sre[p0+3]=v.w;
    sim[p0+0]=0.f; sim[p0+1]=0.f; sim[p0+2]=0.f; sim[p0+3]=0.f;
    int p1 = PADI(i0 + LSIG);
    sre[p1+0]=0.f; sre[p1+1]=0.f; sre[p1+2]=0.f; sre[p1+3]=0.f;
    sim[p1+0]=0.f; sim[p1+1]=0.f; sim[p1+2]=0.f; sim[p1+3]=0.f;
  }
  __syncthreads();
  stage8f<2048,false>(sre, sim, tid); __syncthreads();
  stage8f< 256,false>(sre, sim, tid); __syncthreads();
  stage8f<  32,false>(sre, sim, tid); __syncthreads();
  stage8_s4f<false>(sre, sim, tid);   __syncthreads();

  cplx kq[4][4];
  cplx kq2[4][4];
  const float scl = 1.0f / (float)NFFT;
  #pragma unroll
  for (int s = 0; s < 8; ++s) {
    int m = tid + NTH * s;
    int p = PADI(4 * m);
    cplx z[4] = { {sre[p+0], sim[p+0]}, {sre[p+1], sim[p+1]},
                  {sre[p+2], sim[p+2]}, {sre[p+3], sim[p+3]} };
    fft_regs<4,false>(z);
    #pragma unroll
    for (int e = 0; e < 4; ++e) {
      cplx v = {z[e].x*scl, z[e].y*scl};
      if (s < 4) kq[s][e] = v; else kq2[s-4][e] = v;
    }
  }
  __syncthreads();

  const float* u0 = u + ((size_t)(2*pr) * NH + h) * LSIG;
  const float* u1 = u0 + (size_t)NH * LSIG;
  #pragma unroll
  for (int c = 0; c < 4; ++c) {
    int i0 = (c * NTH + tid) * 4;
    float4 a = *reinterpret_cast<const float4*>(u0 + i0);
    float4 b = *reinterpret_cast<const float4*>(u1 + i0);
    int p0 = PADI(i0);
    sre[p0+0]=a.x; sre[p0+1]=a.y; sre[p0+2]=a.z; sre[p0+3]=a.w;
    sim[p0+0]=b.x; sim[p0+1]=b.y; sim[p0+2]=b.z; sim[p0+3]=b.w;
    int p1 = PADI(i0 + LSIG);
    sre[p1+0]=0.f; sre[p1+1]=0.f; sre[p1+2]=0.f; sre[p1+3]=0.f;
    sim[p1+0]=0.f; sim[p1+1]=0.f; sim[p1+2]=0.f; sim[p1+3]=0.f;
  }
  __syncthreads();
  stage8f<2048,false>(sre, sim, tid); __syncthreads();
  stage8f< 256,false>(sre, sim, tid); __syncthreads();
  stage8f<  32,false>(sre, sim, tid); __syncthreads();
  stage8_s4f<false>(sre, sim, tid);   __syncthreads();

  #pragma unroll
  for (int s = 0; s < 8; ++s) {
    int m = tid + NTH * s;
    int p = PADI(4 * m);
    cplx z[4] = { {sre[p+0], sim[p+0]}, {sre[p+1], sim[p+1]},
                  {sre[p+2], sim[p+2]}, {sre[p+3], sim[p+3]} };
    fft_regs<4,false>(z);
    #pragma unroll
    for (int e = 0; e < 4; ++e) z[e] = cmul(z[e], (s<4) ? kq[s][e] : kq2[s-4][e]);
    fft_regs<4,true>(z);
    #pragma unroll
    for (int e = 0; e < 4; ++e) { sre[p+e] = z[e].x; sim[p+e] = z[e].y; }
  }
  __syncthreads();
  stage8_s4f<true>(sre, sim, tid);   __syncthreads();
  stage8f<  32,true>(sre, sim, tid); __syncthreads();
  stage8f< 256,true>(sre, sim, tid); __syncthreads();
  stage8f<2048,true>(sre, sim, tid); __syncthreads();

  float* o0 = out + ((size_t)(2*pr) * NH + h) * LSIG;
  float* o1 = o0 + (size_t)NH * LSIG;
  #pragma unroll
  for (int c = 0; c < 4; ++c) {
    int i0 = (c * NTH + tid) * 4;
    int p0 = PADI(i0);
    float4 a = {sre[p0], sre[p0+1], sre[p0+2], sre[p0+3]};
    float4 b = {sim[p0], sim[p0+1], sim[p0+2], sim[p0+3]};
    *reinterpret_cast<float4*>(o0 + i0) = a;
    *reinterpret_cast<float4*>(o1 + i0) = b;
  }
}

extern "C" void kernel_launch(void* const* d_in, const int* in_sizes, int n_in,
                              void* d_out, int out_size, void* d_ws, size_t ws_size,
                              hipStream_t stream) {
  (void)in_sizes; (void)n_in; (void)out_size;
  const float* u = (const float*)d_in[0];
  const float* k = (const float*)d_in[1];
  float* out = (float*)d_out;
  const size_t need = (size_t)NH * NFFT * sizeof(float2);   // 128 MiB
  if (ws_size >= need) {
    hipLaunchKernelGGL(kfft_kernel, dim3(NH),   dim3(NTH), 0, stream, k, (float2*)d_ws);
    hipLaunchKernelGGL(conv_kernel, dim3(4096), dim3(NTH), 0, stream, u, (const float2*)d_ws, out);
  } else {
    hipLaunchKernelGGL(fftconv_fallback, dim3(4096), dim3(NTH), 0, stream, u, k, out);
  }
}

// Round 17
// 374.206 us; speedup vs baseline: 5.6662x; 1.0016x over previous
//
#include <hip/hip_runtime.h>

#define NFFT 16384
#define LSIG 8192
#define NH   1024
#define NTH  512
#define LDSC (NFFT + ((NFFT >> 5) << 1))   // 17408 complexes, pad 2/32, b128-safe

__device__ __forceinline__ int PADC(int i) { return i + ((i >> 5) << 1); }
__device__ __forceinline__ int PADI(int i) { return i + (i >> 5); }   // fallback

struct cplx { float x, y; };
__device__ __forceinline__ cplx cadd(cplx a, cplx b){ return {a.x+b.x, a.y+b.y}; }
__device__ __forceinline__ cplx csub(cplx a, cplx b){ return {a.x-b.x, a.y-b.y}; }
__device__ __forceinline__ cplx cmul(cplx a, cplx b){ return {a.x*b.x - a.y*b.y, a.x*b.y + a.y*b.x}; }

template<int V> struct ic { static constexpr int value = V; };
template<int Start, int End, typename F>
__device__ __forceinline__ void cfor(F&& f) {
  if constexpr (Start < End) { f(ic<Start>{}); cfor<Start+1, End>(static_cast<F&&>(f)); }
}

constexpr float W32C32[32] = {
  1.0f, 0.9807852804f, 0.9238795325f, 0.8314696123f,
  0.7071067812f, 0.5555702330f, 0.3826834324f, 0.1950903220f,
  0.0f, -0.1950903220f, -0.3826834324f, -0.5555702330f,
  -0.7071067812f, -0.8314696123f, -0.9238795325f, -0.9807852804f,
  -1.0f, -0.9807852804f, -0.9238795325f, -0.8314696123f,
  -0.7071067812f, -0.5555702330f, -0.3826834324f, -0.1950903220f,
  0.0f, 0.1950903220f, 0.3826834324f, 0.5555702330f,
  0.7071067812f, 0.8314696123f, 0.9238795325f, 0.9807852804f };
constexpr float W32S32[32] = {
  0.0f, 0.1950903220f, 0.3826834324f, 0.5555702330f,
  0.7071067812f, 0.8314696123f, 0.9238795325f, 0.9807852804f,
  1.0f, 0.9807852804f, 0.9238795325f, 0.8314696123f,
  0.7071067812f, 0.5555702330f, 0.3826834324f, 0.1950903220f,
  0.0f, -0.1950903220f, -0.3826834324f, -0.5555702330f,
  -0.7071067812f, -0.8314696123f, -0.9238795325f, -0.9807852804f,
  -1.0f, -0.9807852804f, -0.9238795325f, -0.8314696123f,
  -0.7071067812f, -0.5555702330f, -0.3826834324f, -0.1950903220f };
constexpr int BR3[8] = {0,4,2,6,1,5,3,7};

template<int KK, bool INV>
__device__ __forceinline__ cplx twid(cplx d) {
  constexpr int K = KK & 31;
  if constexpr (K == 0)       return d;
  else if constexpr (K == 8)  { if constexpr (INV) return cplx{-d.y, d.x}; else return cplx{d.y, -d.x}; }
  else if constexpr (K == 16) return cplx{-d.x, -d.y};
  else if constexpr (K == 24) { if constexpr (INV) return cplx{d.y, -d.x}; else return cplx{-d.y, d.x}; }
  else {
    constexpr float c = W32C32[K];
    constexpr float s = INV ? W32S32[K] : -W32S32[K];
    return cmul(d, cplx{c, s});
  }
}

template<int N, int SP, bool INV>
__device__ __forceinline__ void fft_pass(cplx* z) {
  #pragma unroll
  for (int b = 0; b < N; b += 2*SP) {
    cfor<0, SP>([&](auto rc){
      constexpr int r = decltype(rc)::value;
      constexpr int KK = r * (16 / SP);
      if constexpr (!INV) {
        cplx u = z[b+r], v = z[b+r+SP];
        z[b+r]    = cadd(u, v);
        z[b+r+SP] = twid<KK,false>(csub(u, v));
      } else {
        cplx t0 = z[b+r], t1 = z[b+r+SP];
        cplx w = twid<KK,true>(t1);
        z[b+r]    = cadd(t0, w);
        z[b+r+SP] = csub(t0, w);
      }
    });
  }
}

template<int N, bool INV>
__device__ __forceinline__ void fft_regs(cplx* z) {
  if constexpr (!INV) {
    if constexpr (N >= 32) fft_pass<N,16,false>(z);
    if constexpr (N >= 16) fft_pass<N, 8,false>(z);
    if constexpr (N >=  8) fft_pass<N, 4,false>(z);
    if constexpr (N >=  4) fft_pass<N, 2,false>(z);
    fft_pass<N,1,false>(z);
  } else {
    fft_pass<N,1,true>(z);
    if constexpr (N >=  4) fft_pass<N, 2,true>(z);
    if constexpr (N >=  8) fft_pass<N, 4,true>(z);
    if constexpr (N >= 16) fft_pass<N, 8,true>(z);
    if constexpr (N >= 32) fft_pass<N,16,true>(z);
  }
}

// Generic paired radix-8 LDS stage (block-mapped; used by fallback path only
// for S=256 pre-r17; kept for stage-1-less shapes).
template<int S, bool INV>
__device__ __forceinline__ void stage8p(float2* sz, int tid) {
  const float ang1 = (INV ? 2.0f : -2.0f) * 3.14159265358979f / (float)(8 * S);
  #pragma unroll 1
  for (int it = 0; it < 2; ++it) {
    int pp = tid + it * NTH;
    int bf = 2 * pp;
    int q = bf / S;
    int r = bf - q * S;
    int base = q * (8 * S) + r;
    float ta = ang1 * (float)r;
    float tb = ang1 * (float)(r + 1);
    cplx w1a = {__cosf(ta), __sinf(ta)};
    cplx w1b = {__cosf(tb), __sinf(tb)};
    cplx wa[8], wb[8];
    wa[1]=w1a; wa[2]=cmul(w1a,w1a); wa[3]=cmul(wa[2],w1a); wa[4]=cmul(wa[2],wa[2]);
    wa[5]=cmul(wa[4],wa[1]); wa[6]=cmul(wa[4],wa[2]); wa[7]=cmul(wa[4],wa[3]);
    wb[1]=w1b; wb[2]=cmul(w1b,w1b); wb[3]=cmul(wb[2],w1b); wb[4]=cmul(wb[2],wb[2]);
    wb[5]=cmul(wb[4],wb[1]); wb[6]=cmul(wb[4],wb[2]); wb[7]=cmul(wb[4],wb[3]);

    cplx A[8], B[8];
    if constexpr (!INV) {
      cfor<0,8>([&](auto jc){ constexpr int j = decltype(jc)::value;
        float4 v = *reinterpret_cast<const float4*>(&sz[PADC(base + j*S)]);
        A[j] = {v.x, v.y}; B[j] = {v.z, v.w}; });
      fft_regs<8,false>(A);
      fft_regs<8,false>(B);
      cfor<0,8>([&](auto pc){ constexpr int p = decltype(pc)::value;
        constexpr int m = BR3[p];
        cplx oa, ob;
        if constexpr (m == 0) { oa = A[p]; ob = B[p]; }
        else { oa = cmul(A[p], wa[m]); ob = cmul(B[p], wb[m]); }
        *reinterpret_cast<float4*>(&sz[PADC(base + m*S)]) = make_float4(oa.x, oa.y, ob.x, ob.y); });
    } else {
      cfor<0,8>([&](auto pc){ constexpr int p = decltype(pc)::value;
        constexpr int m = BR3[p];
        float4 v = *reinterpret_cast<const float4*>(&sz[PADC(base + m*S)]);
        if constexpr (m == 0) { A[p] = {v.x, v.y}; B[p] = {v.z, v.w}; }
        else { A[p] = cmul(cplx{v.x, v.y}, wa[m]); B[p] = cmul(cplx{v.z, v.w}, wb[m]); } });
      fft_regs<8,true>(A);
      fft_regs<8,true>(B);
      cfor<0,8>([&](auto jc){ constexpr int j = decltype(jc)::value;
        *reinterpret_cast<float4*>(&sz[PADC(base + j*S)]) = make_float4(A[j].x, A[j].y, B[j].x, B[j].y); });
    }
  }
}

// S=256 stage, WAVE-LOCAL: sub-problem q = wave (8 sub-problems = 8 waves),
// r = 2*(lane + 64*it). Wave w owns complexes [2048w, 2048w+2048) exactly.
// Same per-lane 16B-stride pattern as the block mapping -> same banks.
template<bool INV>
__device__ __forceinline__ void stage8p256w(float2* sz, int tid) {
  const float ang1 = (INV ? 2.0f : -2.0f) * 3.14159265358979f / 2048.0f;
  const int w = tid >> 6, lane = tid & 63;
  #pragma unroll 1
  for (int it = 0; it < 2; ++it) {
    int r = 2 * (lane + 64 * it);       // even, r+1 < 256
    int base = w * 2048 + r;
    float ta = ang1 * (float)r;
    float tb = ang1 * (float)(r + 1);
    cplx w1a = {__cosf(ta), __sinf(ta)};
    cplx w1b = {__cosf(tb), __sinf(tb)};
    cplx wa[8], wb[8];
    wa[1]=w1a; wa[2]=cmul(w1a,w1a); wa[3]=cmul(wa[2],w1a); wa[4]=cmul(wa[2],wa[2]);
    wa[5]=cmul(wa[4],wa[1]); wa[6]=cmul(wa[4],wa[2]); wa[7]=cmul(wa[4],wa[3]);
    wb[1]=w1b; wb[2]=cmul(w1b,w1b); wb[3]=cmul(wb[2],w1b); wb[4]=cmul(wb[2],wb[2]);
    wb[5]=cmul(wb[4],wb[1]); wb[6]=cmul(wb[4],wb[2]); wb[7]=cmul(wb[4],wb[3]);

    cplx A[8], B[8];
    if constexpr (!INV) {
      cfor<0,8>([&](auto jc){ constexpr int j = decltype(jc)::value;
        float4 v = *reinterpret_cast<const float4*>(&sz[PADC(base + j*256)]);
        A[j] = {v.x, v.y}; B[j] = {v.z, v.w}; });
      fft_regs<8,false>(A);
      fft_regs<8,false>(B);
      cfor<0,8>([&](auto pc){ constexpr int p = decltype(pc)::value;
        constexpr int m = BR3[p];
        cplx oa, ob;
        if constexpr (m == 0) { oa = A[p]; ob = B[p]; }
        else { oa = cmul(A[p], wa[m]); ob = cmul(B[p], wb[m]); }
        *reinterpret_cast<float4*>(&sz[PADC(base + m*256)]) = make_float4(oa.x, oa.y, ob.x, ob.y); });
    } else {
      cfor<0,8>([&](auto pc){ constexpr int p = decltype(pc)::value;
        constexpr int m = BR3[p];
        float4 v = *reinterpret_cast<const float4*>(&sz[PADC(base + m*256)]);
        if constexpr (m == 0) { A[p] = {v.x, v.y}; B[p] = {v.z, v.w}; }
        else { A[p] = cmul(cplx{v.x, v.y}, wa[m]); B[p] = cmul(cplx{v.z, v.w}, wb[m]); } });
      fft_regs<8,true>(A);
      fft_regs<8,true>(B);
      cfor<0,8>([&](auto jc){ constexpr int j = decltype(jc)::value;
        *reinterpret_cast<float4*>(&sz[PADC(base + j*256)]) = make_float4(A[j].x, A[j].y, B[j].x, B[j].y); });
    }
  }
}

// S=32 stage, wave-local (round-16, verified): pp = 128*wave + lane + 64*it.
template<bool INV>
__device__ __forceinline__ void stage8p32w(float2* sz, int tid) {
  const float ang1 = (INV ? 2.0f : -2.0f) * 3.14159265358979f / 256.0f;
  #pragma unroll 1
  for (int it = 0; it < 2; ++it) {
    int pp = 128 * (tid >> 6) + (tid & 63) + 64 * it;
    int bf = 2 * pp;
    int q = bf >> 5;
    int r = bf & 31;
    int base = q * 256 + r;
    float ta = ang1 * (float)r;
    float tb = ang1 * (float)(r + 1);
    cplx w1a = {__cosf(ta), __sinf(ta)};
    cplx w1b = {__cosf(tb), __sinf(tb)};
    cplx wa[8], wb[8];
    wa[1]=w1a; wa[2]=cmul(w1a,w1a); wa[3]=cmul(wa[2],w1a); wa[4]=cmul(wa[2],wa[2]);
    wa[5]=cmul(wa[4],wa[1]); wa[6]=cmul(wa[4],wa[2]); wa[7]=cmul(wa[4],wa[3]);
    wb[1]=w1b; wb[2]=cmul(w1b,w1b); wb[3]=cmul(wb[2],w1b); wb[4]=cmul(wb[2],wb[2]);
    wb[5]=cmul(wb[4],wb[1]); wb[6]=cmul(wb[4],wb[2]); wb[7]=cmul(wb[4],wb[3]);

    cplx A[8], B[8];
    if constexpr (!INV) {
      cfor<0,8>([&](auto jc){ constexpr int j = decltype(jc)::value;
        float4 v = *reinterpret_cast<const float4*>(&sz[PADC(base + j*32)]);
        A[j] = {v.x, v.y}; B[j] = {v.z, v.w}; });
      fft_regs<8,false>(A);
      fft_regs<8,false>(B);
      cfor<0,8>([&](auto pc){ constexpr int p = decltype(pc)::value;
        constexpr int m = BR3[p];
        cplx oa, ob;
        if constexpr (m == 0) { oa = A[p]; ob = B[p]; }
        else { oa = cmul(A[p], wa[m]); ob = cmul(B[p], wb[m]); }
        *reinterpret_cast<float4*>(&sz[PADC(base + m*32)]) = make_float4(oa.x, oa.y, ob.x, ob.y); });
    } else {
      cfor<0,8>([&](auto pc){ constexpr int p = decltype(pc)::value;
        constexpr int m = BR3[p];
        float4 v = *reinterpret_cast<const float4*>(&sz[PADC(base + m*32)]);
        if constexpr (m == 0) { A[p] = {v.x, v.y}; B[p] = {v.z, v.w}; }
        else { A[p] = cmul(cplx{v.x, v.y}, wa[m]); B[p] = cmul(cplx{v.z, v.w}, wb[m]); } });
      fft_regs<8,true>(A);
      fft_regs<8,true>(B);
      cfor<0,8>([&](auto jc){ constexpr int j = decltype(jc)::value;
        *reinterpret_cast<float4*>(&sz[PADC(base + j*32)]) = make_float4(A[j].x, A[j].y, B[j].x, B[j].y); });
    }
  }
}

// Paired S=4 stage: thread-local (base = tid*32), constexpr twiddles.
template<bool INV>
__device__ __forceinline__ void stage8_s4p(float2* sz, int tid) {
  cfor<0,2>([&](auto rrc){
    constexpr int r0 = decltype(rrc)::value * 2;
    int base = tid * 32 + r0;
    cplx A[8], B[8];
    if constexpr (!INV) {
      cfor<0,8>([&](auto jc){ constexpr int j = decltype(jc)::value;
        float4 v = *reinterpret_cast<const float4*>(&sz[PADC(base + j*4)]);
        A[j] = {v.x, v.y}; B[j] = {v.z, v.w}; });
      fft_regs<8,false>(A);
      fft_regs<8,false>(B);
      cfor<0,8>([&](auto pc){ constexpr int p = decltype(pc)::value;
        constexpr int m = BR3[p];
        cplx oa = twid<r0*m, false>(A[p]);
        cplx ob = twid<(r0+1)*m, false>(B[p]);
        *reinterpret_cast<float4*>(&sz[PADC(base + m*4)]) = make_float4(oa.x, oa.y, ob.x, ob.y); });
    } else {
      cfor<0,8>([&](auto pc){ constexpr int p = decltype(pc)::value;
        constexpr int m = BR3[p];
        float4 v = *reinterpret_cast<const float4*>(&sz[PADC(base + m*4)]);
        A[p] = twid<r0*m, true>(cplx{v.x, v.y});
        B[p] = twid<(r0+1)*m, true>(cplx{v.z, v.w});
      });
      fft_regs<8,true>(A);
      fft_regs<8,true>(B);
      cfor<0,8>([&](auto jc){ constexpr int j = decltype(jc)::value;
        *reinterpret_cast<float4*>(&sz[PADC(base + j*4)]) = make_float4(A[j].x, A[j].y, B[j].x, B[j].y); });
    }
  });
}

// ---------- kernel 1: K-spectrum, stored TRANSPOSED for coalesced conv reads:
// kh[h*NFFT + s*2048 + 4*tid + e]  (thread tid's quad s = spectrum 32tid+4s)
__global__ __launch_bounds__(NTH)
void kfft_kernel(const float* __restrict__ kin, float2* __restrict__ kh) {
  __shared__ __align__(16) float2 sz[LDSC];
  const int tid = threadIdx.x;
  const int h = blockIdx.x;
  const float* krow = kin + (size_t)h * LSIG;
  const float ang1 = -2.0f * 3.14159265358979f / (float)NFFT;

  // stage 1 (S=2048) fused with global load; upper half of input is zero.
  #pragma unroll 1
  for (int it = 0; it < 2; ++it) {
    int base = 2*tid + 1024*it;
    cplx A[8], B[8];
    cfor<0,4>([&](auto jc){ constexpr int j = decltype(jc)::value;
      float2 kr = *reinterpret_cast<const float2*>(krow + base + j*2048);
      A[j] = {kr.x, 0.f}; B[j] = {kr.y, 0.f}; });
    cfor<0,4>([&](auto jc){ constexpr int j = decltype(jc)::value;   // half-zero SP=4
      A[j+4] = twid<4*j,false>(A[j]);
      B[j+4] = twid<4*j,false>(B[j]); });
    fft_pass<8,2,false>(A); fft_pass<8,1,false>(A);
    fft_pass<8,2,false>(B); fft_pass<8,1,false>(B);
    float ta = ang1 * (float)base, tb = ang1 * (float)(base + 1);
    cplx w1a = {__cosf(ta), __sinf(ta)};
    cplx w1b = {__cosf(tb), __sinf(tb)};
    cplx wa[8], wb[8];
    wa[1]=w1a; wa[2]=cmul(w1a,w1a); wa[3]=cmul(wa[2],w1a); wa[4]=cmul(wa[2],wa[2]);
    wa[5]=cmul(wa[4],wa[1]); wa[6]=cmul(wa[4],wa[2]); wa[7]=cmul(wa[4],wa[3]);
    wb[1]=w1b; wb[2]=cmul(w1b,w1b); wb[3]=cmul(wb[2],w1b); wb[4]=cmul(wb[2],wb[2]);
    wb[5]=cmul(wb[4],wb[1]); wb[6]=cmul(wb[4],wb[2]); wb[7]=cmul(wb[4],wb[3]);
    cfor<0,8>([&](auto pc){ constexpr int p = decltype(pc)::value;
      constexpr int m = BR3[p];
      cplx oa, ob;
      if constexpr (m == 0) { oa = A[p]; ob = B[p]; }
      else { oa = cmul(A[p], wa[m]); ob = cmul(B[p], wb[m]); }
      *reinterpret_cast<float4*>(&sz[PADC(base + m*2048)]) = make_float4(oa.x, oa.y, ob.x, ob.y); });
  }
  __syncthreads();
  stage8p256w<false>(sz, tid);              // wave-local from here on
  stage8p32w<false>(sz, tid);
  stage8_s4p<false>(sz, tid);

  const float scl = 1.0f / (float)NFFT;
  float2* row = kh + (size_t)h * NFFT;
  #pragma unroll
  for (int s = 0; s < 8; ++s) {             // quads in this thread's 32 complexes
    int ci = 32*tid + 4*s;
    float4 f0 = *reinterpret_cast<const float4*>(&sz[PADC(ci)]);
    float4 f1 = *reinterpret_cast<const float4*>(&sz[PADC(ci + 2)]);
    cplx z[4] = { {f0.x, f0.y}, {f0.z, f0.w}, {f1.x, f1.y}, {f1.z, f1.w} };
    fft_regs<4,false>(z);
    float2* dst = row + s*2048 + 4*tid;     // transposed: coalesced write
    *reinterpret_cast<float4*>(dst)     = make_float4(z[0].x*scl, z[0].y*scl, z[1].x*scl, z[1].y*scl);
    *reinterpret_cast<float4*>(dst + 2) = make_float4(z[2].x*scl, z[2].y*scl, z[3].x*scl, z[3].y*scl);
  }
}

// ---------- kernel 2: conv — only TWO block barriers (around stage-1) -------
__global__ __launch_bounds__(NTH)
void conv_kernel(const float* __restrict__ u, const float2* __restrict__ kh,
                 float* __restrict__ out) {
  __shared__ __align__(16) float2 sz[LDSC];
  const int tid = threadIdx.x;
  const int bid = blockIdx.x;
  const int h  = bid >> 2;            // 4 same-h blocks adjacent -> K-hat reuse
  const int pr = bid & 3;

  const float* u0 = u + ((size_t)(2*pr) * NH + h) * LSIG;
  const float* u1 = u0 + (size_t)NH * LSIG;
  float* o0 = out + ((size_t)(2*pr) * NH + h) * LSIG;
  float* o1 = o0 + (size_t)NH * LSIG;

  // ---- stage 1 forward, fused with global load (upper half zero) ----
  {
    const float ang1 = -2.0f * 3.14159265358979f / (float)NFFT;
    #pragma unroll 1
    for (int it = 0; it < 2; ++it) {
      int base = 2*tid + 1024*it;
      cplx A[8], B[8];
      cfor<0,4>([&](auto jc){ constexpr int j = decltype(jc)::value;
        float2 a2 = *reinterpret_cast<const float2*>(u0 + base + j*2048);
        float2 b2 = *reinterpret_cast<const float2*>(u1 + base + j*2048);
        A[j] = {a2.x, b2.x}; B[j] = {a2.y, b2.y}; });
      cfor<0,4>([&](auto jc){ constexpr int j = decltype(jc)::value;   // half-zero SP=4
        A[j+4] = twid<4*j,false>(A[j]);
        B[j+4] = twid<4*j,false>(B[j]); });
      fft_pass<8,2,false>(A); fft_pass<8,1,false>(A);
      fft_pass<8,2,false>(B); fft_pass<8,1,false>(B);
      float ta = ang1 * (float)base, tb = ang1 * (float)(base + 1);
      cplx w1a = {__cosf(ta), __sinf(ta)};
      cplx w1b = {__cosf(tb), __sinf(tb)};
      cplx wa[8], wb[8];
      wa[1]=w1a; wa[2]=cmul(w1a,w1a); wa[3]=cmul(wa[2],w1a); wa[4]=cmul(wa[2],wa[2]);
      wa[5]=cmul(wa[4],wa[1]); wa[6]=cmul(wa[4],wa[2]); wa[7]=cmul(wa[4],wa[3]);
      wb[1]=w1b; wb[2]=cmul(w1b,w1b); wb[3]=cmul(wb[2],w1b); wb[4]=cmul(wb[2],wb[2]);
      wb[5]=cmul(wb[4],wb[1]); wb[6]=cmul(wb[4],wb[2]); wb[7]=cmul(wb[4],wb[3]);
      cfor<0,8>([&](auto pc){ constexpr int p = decltype(pc)::value;
        constexpr int m = BR3[p];
        cplx oa, ob;
        if constexpr (m == 0) { oa = A[p]; ob = B[p]; }
        else { oa = cmul(A[p], wa[m]); ob = cmul(B[p], wb[m]); }
        *reinterpret_cast<float4*>(&sz[PADC(base + m*2048)]) = make_float4(oa.x, oa.y, ob.x, ob.y); });
    }
  }
  __syncthreads();

  // ---- wave-local region: s256 -> s32 -> s4 -> quad*Khat -> inverses -------
  stage8p256w<false>(sz, tid);
  stage8p32w<false>(sz, tid);
  stage8_s4p<false>(sz, tid);
  {
    const float2* kp = kh + (size_t)h * NFFT;
    #pragma unroll
    for (int s = 0; s < 8; ++s) {
      int ci = 32*tid + 4*s;
      float4 f0 = *reinterpret_cast<const float4*>(&sz[PADC(ci)]);
      float4 f1 = *reinterpret_cast<const float4*>(&sz[PADC(ci + 2)]);
      cplx z[4] = { {f0.x, f0.y}, {f0.z, f0.w}, {f1.x, f1.y}, {f1.z, f1.w} };
      fft_regs<4,false>(z);
      const float2* kq = kp + s*2048 + 4*tid;          // coalesced (2KB/wave)
      float4 k0 = *reinterpret_cast<const float4*>(kq);
      float4 k1 = *reinterpret_cast<const float4*>(kq + 2);
      z[0] = cmul(z[0], cplx{k0.x, k0.y});
      z[1] = cmul(z[1], cplx{k0.z, k0.w});
      z[2] = cmul(z[2], cplx{k1.x, k1.y});
      z[3] = cmul(z[3], cplx{k1.z, k1.w});
      fft_regs<4,true>(z);
      *reinterpret_cast<float4*>(&sz[PADC(ci)])     = make_float4(z[0].x, z[0].y, z[1].x, z[1].y);
      *reinterpret_cast<float4*>(&sz[PADC(ci + 2)]) = make_float4(z[2].x, z[2].y, z[3].x, z[3].y);
    }
  }
  stage8_s4p<true>(sz, tid);
  stage8p32w<true>(sz, tid);
  stage8p256w<true>(sz, tid);
  __syncthreads();

  // ---- stage 1 inverse, fused with output (only first 8192 samples kept) ----
  {
    const float ang1 = 2.0f * 3.14159265358979f / (float)NFFT;
    #pragma unroll 1
    for (int it = 0; it < 2; ++it) {
      int base = 2*tid + 1024*it;
      float ta = ang1 * (float)base, tb = ang1 * (float)(base + 1);
      cplx w1a = {__cosf(ta), __sinf(ta)};
      cplx w1b = {__cosf(tb), __sinf(tb)};
      cplx wa[8], wb[8];
      wa[1]=w1a; wa[2]=cmul(w1a,w1a); wa[3]=cmul(wa[2],w1a); wa[4]=cmul(wa[2],wa[2]);
      wa[5]=cmul(wa[4],wa[1]); wa[6]=cmul(wa[4],wa[2]); wa[7]=cmul(wa[4],wa[3]);
      wb[1]=w1b; wb[2]=cmul(w1b,w1b); wb[3]=cmul(wb[2],w1b); wb[4]=cmul(wb[2],wb[2]);
      wb[5]=cmul(wb[4],wb[1]); wb[6]=cmul(wb[4],wb[2]); wb[7]=cmul(wb[4],wb[3]);
      cplx A[8], B[8];
      cfor<0,8>([&](auto pc){ constexpr int p = decltype(pc)::value;
        constexpr int m = BR3[p];
        float4 v = *reinterpret_cast<const float4*>(&sz[PADC(base + m*2048)]);
        if constexpr (m == 0) { A[p] = {v.x, v.y}; B[p] = {v.z, v.w}; }
        else { A[p] = cmul(cplx{v.x, v.y}, wa[m]); B[p] = cmul(cplx{v.z, v.w}, wb[m]); } });
      fft_pass<8,1,true>(A); fft_pass<8,2,true>(A);
      fft_pass<8,1,true>(B); fft_pass<8,2,true>(B);
      // final SP=4 pass, '+' half only (outputs j=0..3 are samples < 8192)
      cfor<0,4>([&](auto rc){ constexpr int r = decltype(rc)::value;
        cplx yA = cadd(A[r], twid<4*r,true>(A[r+4]));
        cplx yB = cadd(B[r], twid<4*r,true>(B[r+4]));
        *reinterpret_cast<float2*>(o0 + base + r*2048) = make_float2(yA.x, yB.x);
        *reinterpret_cast<float2*>(o1 + base + r*2048) = make_float2(yA.y, yB.y); });
    }
  }
}

// ================= fallback (round-9/10 monolithic, known-good) =============
template<int S, bool INV>
__device__ __forceinline__ void stage8f(float* sre, float* sim, int tid) {
  const float ang1 = (INV ? 2.0f : -2.0f) * 3.14159265358979f / (float)(8 * S);
  #pragma unroll
  for (int it = 0; it < (NFFT/8)/NTH; ++it) {
    int bf = tid + it * NTH;
    int q = bf / S;
    int r = bf - q * S;
    int base = q * (8 * S) + r;
    float t = ang1 * (float)r;
    cplx w1 = {__cosf(t), __sinf(t)};
    cplx wp[8];
    wp[0] = {1.0f, 0.0f};
    wp[1] = w1; wp[2] = cmul(w1, w1); wp[3] = cmul(wp[2], w1); wp[4] = cmul(wp[2], wp[2]);
    wp[5] = cmul(wp[4], wp[1]); wp[6] = cmul(wp[4], wp[2]); wp[7] = cmul(wp[4], wp[3]);
    cplx a[8];
    if constexpr (!INV) {
      cfor<0,8>([&](auto jc){ constexpr int j = decltype(jc)::value;
        int idx = PADI(base + j*S); a[j] = {sre[idx], sim[idx]}; });
      fft_regs<8,false>(a);
      cfor<0,8>([&](auto pc){ constexpr int p = decltype(pc)::value;
        constexpr int m = BR3[p];
        cplx o; if constexpr (m == 0) o = a[p]; else o = cmul(a[p], wp[m]);
        int idx = PADI(base + m*S); sre[idx] = o.x; sim[idx] = o.y; });
    } else {
      cfor<0,8>([&](auto pc){ constexpr int p = decltype(pc)::value;
        constexpr int m = BR3[p];
        int idx = PADI(base + m*S); cplx v = {sre[idx], sim[idx]};
        if constexpr (m == 0) a[p] = v; else a[p] = cmul(v, wp[m]); });
      fft_regs<8,true>(a);
      cfor<0,8>([&](auto jc){ constexpr int j = decltype(jc)::value;
        int idx = PADI(base + j*S); sre[idx] = a[j].x; sim[idx] = a[j].y; });
    }
  }
}

template<bool INV>
__device__ __forceinline__ void stage8_s4f(float* sre, float* sim, int tid) {
  cfor<0,4>([&](auto rc){
    constexpr int r = decltype(rc)::value;
    int base = tid * 32 + r;
    cplx a[8];
    if constexpr (!INV) {
      cfor<0,8>([&](auto jc){ constexpr int j = decltype(jc)::value;
        int idx = PADI(base + j*4); a[j] = {sre[idx], sim[idx]}; });
      fft_regs<8,false>(a);
      cfor<0,8>([&](auto pc){ constexpr int p = decltype(pc)::value;
        constexpr int m = BR3[p];
        cplx o = twid<r*m, false>(a[p]);
        int idx = PADI(base + m*4); sre[idx] = o.x; sim[idx] = o.y; });
    } else {
      cfor<0,8>([&](auto pc){ constexpr int p = decltype(pc)::value;
        constexpr int m = BR3[p];
        int idx = PADI(base + m*4); cplx v = {sre[idx], sim[idx]};
        a[p] = twid<r*m, true>(v); });
      fft_regs<8,true>(a);
      cfor<0,8>([&](auto jc){ constexpr int j = decltype(jc)::value;
        int idx = PADI(base + j*4); sre[idx] = a[j].x; sim[idx] = a[j].y; });
    }
  });
}

__global__ __launch_bounds__(NTH)
void fftconv_fallback(const float* __restrict__ u, const float* __restrict__ kin,
                      float* __restrict__ out) {
  __shared__ float sre[NFFT + (NFFT >> 5)];
  __shared__ float sim[NFFT + (NFFT >> 5)];
  const int tid = threadIdx.x;
  const int bid = blockIdx.x;
  const int h  = bid >> 2;
  const int pr = bid & 3;

  const float* krow = kin + (size_t)h * LSIG;
  #pragma unroll
  for (int c = 0; c < 4; ++c) {
    int i0 = (c * NTH + tid) * 4;
    float4 v = *reinterpret_cast<const float4*>(krow + i0);
    int p0 = PADI(i0);
    sre[p0+0]=v.x; sre[p0+1]=v.y; sre[p0+2]=v.z; sre[p0+3]=v.w;
    sim[p0+0]=0.f; sim[p0+1]=0.f; sim[p0+2]=0.f; sim[p0+3]=0.f;
    int p1 = PADI(i0 + LSIG);
    sre[p1+0]=0.f; sre[p1+1]=0.f; sre[p1+2]=0.f; sre[p1+3]=0.f;
    sim[p1+0]=0.f; sim[p1+1]=0.f; sim[p1+2]=0.f; sim[p1+3]=0.f;
  }
  __syncthreads();
  stage8f<2048,false>(sre, sim, tid); __syncthreads();
  stage8f< 256,false>(sre, sim, tid); __syncthreads();
  stage8f<  32,false>(sre, sim, tid); __syncthreads();
  stage8_s4f<false>(sre, sim, tid);   __syncthreads();

  cplx kq[4][4];
  cplx kq2[4][4];
  const float scl = 1.0f / (float)NFFT;
  #pragma unroll
  for (int s = 0; s < 8; ++s) {
    int m = tid + NTH * s;
    int p = PADI(4 * m);
    cplx z[4] = { {sre[p+0], sim[p+0]}, {sre[p+1], sim[p+1]},
                  {sre[p+2], sim[p+2]}, {sre[p+3], sim[p+3]} };
    fft_regs<4,false>(z);
    #pragma unroll
    for (int e = 0; e < 4; ++e) {
      cplx v = {z[e].x*scl, z[e].y*scl};
      if (s < 4) kq[s][e] = v; else kq2[s-4][e] = v;
    }
  }
  __syncthreads();

  const float* u0 = u + ((size_t)(2*pr) * NH + h) * LSIG;
  const float* u1 = u0 + (size_t)NH * LSIG;
  #pragma unroll
  for (int c = 0; c < 4; ++c) {
    int i0 = (c * NTH + tid) * 4;
    float4 a = *reinterpret_cast<const float4*>(u0 + i0);
    float4 b = *reinterpret_cast<const float4*>(u1 + i0);
    int p0 = PADI(i0);
    sre[p0+0]=a.x; sre[p0+1]=a.y; sre[p0+2]=a.z; sre[p0+3]=a.w;
    sim[p0+0]=b.x; sim[p0+1]=b.y; sim[p0+2]=b.z; sim[p0+3]=b.w;
    int p1 = PADI(i0 + LSIG);
    sre[p1+0]=0.f; sre[p1+1]=0.f; sre[p1+2]=0.f; sre[p1+3]=0.f;
    sim[p1+0]=0.f; sim[p1+1]=0.f; sim[p1+2]=0.f; sim[p1+3]=0.f;
  }
  __syncthreads();
  stage8f<2048,false>(sre, sim, tid); __syncthreads();
  stage8f< 256,false>(sre, sim, tid); __syncthreads();
  stage8f<  32,false>(sre, sim, tid); __syncthreads();
  stage8_s4f<false>(sre, sim, tid);   __syncthreads();

  #pragma unroll
  for (int s = 0; s < 8; ++s) {
    int m = tid + NTH * s;
    int p = PADI(4 * m);
    cplx z[4] = { {sre[p+0], sim[p+0]}, {sre[p+1], sim[p+1]},
                  {sre[p+2], sim[p+2]}, {sre[p+3], sim[p+3]} };
    fft_regs<4,false>(z);
    #pragma unroll
    for (int e = 0; e < 4; ++e) z[e] = cmul(z[e], (s<4) ? kq[s][e] : kq2[s-4][e]);
    fft_regs<4,true>(z);
    #pragma unroll
    for (int e = 0; e < 4; ++e) { sre[p+e] = z[e].x; sim[p+e] = z[e].y; }
  }
  __syncthreads();
  stage8_s4f<true>(sre, sim, tid);   __syncthreads();
  stage8f<  32,true>(sre, sim, tid); __syncthreads();
  stage8f< 256,true>(sre, sim, tid); __syncthreads();
  stage8f<2048,true>(sre, sim, tid); __syncthreads();

  float* o0 = out + ((size_t)(2*pr) * NH + h) * LSIG;
  float* o1 = o0 + (size_t)NH * LSIG;
  #pragma unroll
  for (int c = 0; c < 4; ++c) {
    int i0 = (c * NTH + tid) * 4;
    int p0 = PADI(i0);
    float4 a = {sre[p0], sre[p0+1], sre[p0+2], sre[p0+3]};
    float4 b = {sim[p0], sim[p0+1], sim[p0+2], sim[p0+3]};
    *reinterpret_cast<float4*>(o0 + i0) = a;
    *reinterpret_cast<float4*>(o1 + i0) = b;
  }
}

extern "C" void kernel_launch(void* const* d_in, const int* in_sizes, int n_in,
                              void* d_out, int out_size, void* d_ws, size_t ws_size,
                              hipStream_t stream) {
  (void)in_sizes; (void)n_in; (void)out_size;
  const float* u = (const float*)d_in[0];
  const float* k = (const float*)d_in[1];
  float* out = (float*)d_out;
  const size_t need = (size_t)NH * NFFT * sizeof(float2);   // 128 MiB
  if (ws_size >= need) {
    hipLaunchKernelGGL(kfft_kernel, dim3(NH),   dim3(NTH), 0, stream, k, (float2*)d_ws);
    hipLaunchKernelGGL(conv_kernel, dim3(4096), dim3(NTH), 0, stream, u, (const float2*)d_ws, out);
  } else {
    hipLaunchKernelGGL(fftconv_fallback, dim3(4096), dim3(NTH), 0, stream, u, k, out);
  }
}